// Round 13
// baseline (279.071 us; speedup 1.0000x reference)
//
#include <hip/hip_runtime.h>

#define NN 100000
#define NE 1600000
#define DD 128
#define NG 128
#define NC 10
#define POOL_WAVES 2048

#define B1SH 8                        // coarse bucket = 256 nodes
#define NB1 ((NN + 255) / 256)        // 391 buckets
#define EPB 8192                      // edges per partition block
#define NWG1 ((NE + EPB - 1) / EPB)   // 196 partition blocks
#define GEMM_BLOCKS ((NN + 63) / 64)  // 1563

typedef __attribute__((ext_vector_type(8))) short short8v;   // 8 bf16 (4 VGPRs)
typedef __attribute__((ext_vector_type(4))) float f32x4;     // MFMA acc

// fp32 -> bf16 round-to-nearest-even
__device__ __forceinline__ unsigned short f2bf(float f) {
    unsigned int u = __float_as_uint(f);
    u = (u + 0x7fffu + ((u >> 16) & 1u)) >> 16;
    return (unsigned short)u;
}
__device__ __forceinline__ float bflo(unsigned int p) { return __uint_as_float(p << 16); }
__device__ __forceinline__ float bfhi(unsigned int p) { return __uint_as_float(p & 0xffff0000u); }

// ---------------- GEMM body: outb[r][:] = bf16( X[r][:] @ W )  (unscaled; W self-packed) ------
// frag(n, kk, lane, j): k = kk*32 + (lane>>4)*8 + j, col = n*16 + (lane&15)
template <int IN_BF16>
__device__ __forceinline__ void gemm_body(const void* __restrict__ Xv, const float* __restrict__ W,
                                          unsigned short* __restrict__ outb, int blk,
                                          unsigned short* wlds) {
    int tid = threadIdx.x;
    const float4* W4 = (const float4*)W;
#pragma unroll
    for (int it = 0; it < 16; ++it) {
        int li = it * 256 + tid;       // float4 index into W
        float4 f = W4[li];
        int idx = li * 4;
        int k = idx >> 7, c = idx & 127;
        int kk = k >> 5, hi = (k >> 3) & 3, j = k & 7;
        const float* fp = (const float*)&f;
#pragma unroll
        for (int q = 0; q < 4; ++q) {
            int cc = c + q;
            wlds[(((cc >> 4) * 4 + kk) * 64 + hi * 16 + (cc & 15)) * 8 + j] = f2bf(fp[q]);
        }
    }
    __syncthreads();

    int w = tid >> 6, lane = tid & 63;
    int kg = lane >> 4;  // 0..3
    int rowbase = blk * 64 + w * 16;
    int rl = min(rowbase + (lane & 15), NN - 1);

    short8v a[4];
    if (IN_BF16) {
        const unsigned short* xb = (const unsigned short*)Xv;
#pragma unroll
        for (int kk = 0; kk < 4; ++kk)
            a[kk] = *(const short8v*)(xb + (long)rl * DD + kk * 32 + kg * 8);
    } else {
        const float* xf = (const float*)Xv;
#pragma unroll
        for (int kk = 0; kk < 4; ++kk) {
            float4 f0 = *(const float4*)(xf + (long)rl * DD + kk * 32 + kg * 8);
            float4 f1 = *(const float4*)(xf + (long)rl * DD + kk * 32 + kg * 8 + 4);
            short8v t;
            t[0] = (short)f2bf(f0.x); t[1] = (short)f2bf(f0.y);
            t[2] = (short)f2bf(f0.z); t[3] = (short)f2bf(f0.w);
            t[4] = (short)f2bf(f1.x); t[5] = (short)f2bf(f1.y);
            t[6] = (short)f2bf(f1.z); t[7] = (short)f2bf(f1.w);
            a[kk] = t;
        }
    }

    f32x4 acc[8];
#pragma unroll
    for (int n = 0; n < 8; ++n) acc[n] = (f32x4){0.f, 0.f, 0.f, 0.f};
#pragma unroll
    for (int n = 0; n < 8; ++n) {
#pragma unroll
        for (int kk = 0; kk < 4; ++kk) {
            short8v b = *(const short8v*)(wlds + ((n * 4 + kk) * 64 + lane) * 8);
            acc[n] = __builtin_amdgcn_mfma_f32_16x16x32_bf16(a[kk], b, acc[n], 0, 0, 0);
        }
    }

    // D: col = n*16 + (lane&15), row = rowbase + kg*4 + reg
    int c0 = lane & 15;
#pragma unroll
    for (int reg = 0; reg < 4; ++reg) {
        int row = rowbase + kg * 4 + reg;
        if (row < NN) {
            unsigned short* op = outb + (long)row * DD + c0;
#pragma unroll
            for (int n = 0; n < 8; ++n) op[n * 16] = f2bf(acc[n][reg]);
        }
    }
}

// ---------------- K1 fat kernel: hist (blocks 0..195) | gsum zero (196) | gemm1 (197..) ------
__global__ __launch_bounds__(256) void k1_fused(const int* __restrict__ col, int* __restrict__ hist,
                                                const float* __restrict__ x, const float* __restrict__ W1,
                                                unsigned short* __restrict__ hbuf,
                                                float* __restrict__ gsum) {
    __shared__ unsigned short wlds[16384];  // 32 KB (aliased as int* for hist)
    int bid = blockIdx.x, t = threadIdx.x;
    if (bid < NWG1) {
        int* lh = (int*)wlds;
        for (int i = t; i < NB1; i += 256) lh[i] = 0;
        __syncthreads();
        int base = bid * EPB;
        int lim = min(base + EPB, NE);
#pragma unroll 4
        for (int e = base + t; e < lim; e += 256) atomicAdd(&lh[col[e] >> B1SH], 1);
        __syncthreads();
        for (int i = t; i < NB1; i += 256) hist[i * NWG1 + bid] = lh[i];
    } else if (bid == NWG1) {
        float4* g4 = (float4*)gsum;
        for (int i = t; i < NG * DD / 4; i += 256) g4[i] = make_float4(0, 0, 0, 0);
    } else {
        gemm_body<0>(x, W1, hbuf, bid - NWG1 - 1, wlds);
    }
}

__global__ __launch_bounds__(256) void gemm2_k(const unsigned short* __restrict__ xb,
                                               const float* __restrict__ W2,
                                               unsigned short* __restrict__ outb) {
    __shared__ unsigned short wlds[16384];
    gemm_body<1>(xb, W2, outb, blockIdx.x, wlds);
}

// ---------------- bucket totals + exclusive scan -> bbase (one block) ----------------
__global__ __launch_bounds__(512) void btot_k(const int* __restrict__ hist, int* __restrict__ bbase) {
    __shared__ int tmp[512];
    int t = threadIdx.x;
    int s = 0;
    if (t < NB1) {
        const int* hp = hist + t * NWG1;
        for (int w = 0; w < NWG1; ++w) s += hp[w];
    }
    tmp[t] = s;
    __syncthreads();
    for (int o = 1; o < 512; o <<= 1) {
        int v = (t >= o) ? tmp[t - o] : 0;
        __syncthreads();
        tmp[t] += v;
        __syncthreads();
    }
    if (t < NB1) bbase[t] = tmp[t] - s;
    if (t == 511) bbase[NB1] = tmp[511];  // == NE
}

// ---------------- per-bucket exclusive scan over wgs, seeded by bbase[b] ----------------
__global__ __launch_bounds__(256) void histscan_k(const int* __restrict__ bbase, int* __restrict__ hist) {
    __shared__ int tmp[256];
    int b = blockIdx.x, t = threadIdx.x;
    int v = (t < NWG1) ? hist[b * NWG1 + t] : 0;
    tmp[t] = v;
    __syncthreads();
    for (int o = 1; o < 256; o <<= 1) {
        int u = (t >= o) ? tmp[t - o] : 0;
        __syncthreads();
        tmp[t] += u;
        __syncthreads();
    }
    int excl = tmp[t] - v;
    if (t < NWG1) hist[b * NWG1 + t] = bbase[b] + excl;
}

// ---------------- partition edges into coarse-bucket segments (packed) ----------------
__global__ __launch_bounds__(256) void part1_k(const int* __restrict__ row, const int* __restrict__ col,
                                               const int* __restrict__ hist, int* __restrict__ tmpe) {
    __shared__ int lcur[NB1];
    int t = threadIdx.x, w = blockIdx.x;
    for (int i = t; i < NB1; i += 256) lcur[i] = hist[i * NWG1 + w];
    __syncthreads();
    int base = w * EPB;
    int lim = min(base + EPB, NE);
#pragma unroll 4
    for (int e = base + t; e < lim; e += 256) {
        int c = col[e];
        int pos = atomicAdd(&lcur[c >> B1SH], 1);
        tmpe[pos] = (row[e] << B1SH) | (c & 255);  // src<2^17 -> 25 bits
    }
}

// ---------------- P2: count local degrees, write offs+dinv, scatter to exact CSR ----------------
// csr_src stores src*64 (uint-index into the 2-bf16-per-uint row array)
__global__ __launch_bounds__(512) void part2b_k(const int* __restrict__ bbase, const int* __restrict__ tmpe,
                                                unsigned int* __restrict__ csr_src, int* __restrict__ offs,
                                                float* __restrict__ dinv) {
    __shared__ int lcnt[256];
    __shared__ int lsc[256];
    int b = blockIdx.x, t = threadIdx.x;
    if (t < 256) lcnt[t] = 0;
    __syncthreads();
    int ebeg = bbase[b], eend = bbase[b + 1];
    for (int e = ebeg + t; e < eend; e += 512) atomicAdd(&lcnt[tmpe[e] & 255], 1);
    __syncthreads();
    if (t < 256) lsc[t] = lcnt[t];
    __syncthreads();
    for (int o = 1; o < 256; o <<= 1) {
        int v = (t < 256 && t >= o) ? lsc[t - o] : 0;
        __syncthreads();
        if (t < 256) lsc[t] += v;
        __syncthreads();
    }
    int n0 = b << B1SH;
    if (t < 256) {
        int node = n0 + t;
        if (node < NN) {
            int excl = lsc[t] - lcnt[t];
            offs[node] = ebeg + excl;
            dinv[node] = rsqrtf((float)lcnt[t] + 1.0f);  // +1 self-loop
        }
    }
    if (b == NB1 - 1 && t == 0) offs[NN] = NE;
    __syncthreads();
    if (t < 256) lsc[t] = ebeg + (lsc[t] - lcnt[t]);  // cursors
    __syncthreads();
    for (int e = ebeg + t; e < eend; e += 512) {
        int p = tmpe[e];
        int pos = atomicAdd(&lsc[p & 255], 1);
        csr_src[pos] = (unsigned int)(p >> B1SH) << 6;  // src*64
    }
}

// ---------------- aggregation: 2 nodes per wave (interleaved chains), per-edge dinv[src] -------
// out[i] = relu(dinv[i]*(sum dinv[src]*h[src] + dinv[i]*h[i]) + b), h unscaled bf16
__global__ __launch_bounds__(256) void agg_k(const unsigned int* __restrict__ hpb,
                                             const float* __restrict__ dinv,
                                             const int* __restrict__ offs,
                                             const unsigned int* __restrict__ csr,
                                             const float* __restrict__ bias,
                                             unsigned short* __restrict__ outb) {
    int wv = (blockIdx.x << 2) + (threadIdx.x >> 6);  // 0..49999
    int nA = wv * 2, nB = nA + 1;                     // grid exact: both < NN
    unsigned int lane = threadIdx.x & 63;
    int sA = offs[nA];
    int eA = offs[nA + 1];
    int eB = offs[nB + 1];
    int sB = eA;  // offs[nB] == offs[nA+1]
    float dvA = dinv[nA], dvB = dinv[nB];
    unsigned int pA = hpb[(unsigned int)nA * 64u + lane];
    unsigned int pB = hpb[(unsigned int)nB * 64u + lane];
    float aAx = dvA * bflo(pA), aAy = dvA * bfhi(pA);
    float aBx = dvB * bflo(pB), aBy = dvB * bfhi(pB);

    auto b4 = [&](int e, float& ax, float& ay) {
        unsigned int c0 = csr[e], c1 = csr[e + 1], c2 = csr[e + 2], c3 = csr[e + 3];
        float d0 = dinv[c0 >> 6], d1 = dinv[c1 >> 6], d2 = dinv[c2 >> 6], d3 = dinv[c3 >> 6];
        unsigned int p0 = hpb[c0 + lane], p1 = hpb[c1 + lane];
        unsigned int p2 = hpb[c2 + lane], p3 = hpb[c3 + lane];
        ax = fmaf(d0, bflo(p0), ax); ay = fmaf(d0, bfhi(p0), ay);
        ax = fmaf(d1, bflo(p1), ax); ay = fmaf(d1, bfhi(p1), ay);
        ax = fmaf(d2, bflo(p2), ax); ay = fmaf(d2, bfhi(p2), ay);
        ax = fmaf(d3, bflo(p3), ax); ay = fmaf(d3, bfhi(p3), ay);
    };

    int iA = sA, iB = sB;
    while (iA + 4 <= eA && iB + 4 <= eB) {  // interleave both chains for 2x MLP
        b4(iA, aAx, aAy);
        b4(iB, aBx, aBy);
        iA += 4; iB += 4;
    }
    while (iA + 4 <= eA) { b4(iA, aAx, aAy); iA += 4; }
    while (iB + 4 <= eB) { b4(iB, aBx, aBy); iB += 4; }
    for (; iA < eA; ++iA) {
        unsigned int c = csr[iA];
        float d = dinv[c >> 6];
        unsigned int p = hpb[c + lane];
        aAx = fmaf(d, bflo(p), aAx); aAy = fmaf(d, bfhi(p), aAy);
    }
    for (; iB < eB; ++iB) {
        unsigned int c = csr[iB];
        float d = dinv[c >> 6];
        unsigned int p = hpb[c + lane];
        aBx = fmaf(d, bflo(p), aBx); aBy = fmaf(d, bfhi(p), aBy);
    }
    float2 bb = ((const float2*)bias)[lane];
    ((ushort2*)outb)[(unsigned int)nA * 64u + lane] =
        make_ushort2(f2bf(fmaxf(fmaf(dvA, aAx, bb.x), 0.0f)), f2bf(fmaxf(fmaf(dvA, aAy, bb.y), 0.0f)));
    ((ushort2*)outb)[(unsigned int)nB * 64u + lane] =
        make_ushort2(f2bf(fmaxf(fmaf(dvB, aBx, bb.x), 0.0f)), f2bf(fmaxf(fmaf(dvB, aBy, bb.y), 0.0f)));
}

// ---------------- pooling: 2048 waves over sorted batch (bf16 in), boundary-flush atomics ------
__global__ __launch_bounds__(256) void pool2_k(const unsigned short* __restrict__ h,
                                               const int* __restrict__ batch,
                                               float* __restrict__ gsum) {
    int wave = (blockIdx.x * 256 + threadIdx.x) >> 6;
    int lane = threadIdx.x & 63;
    const int per = (NN + POOL_WAVES - 1) / POOL_WAVES;  // 49
    int s = wave * per;
    int e = min(s + per, NN);
    if (s >= e) return;
    const unsigned int* h2 = (const unsigned int*)h;
    float2 acc = {0.0f, 0.0f};
    int cur = batch[s];
    for (int r = s; r < e; ++r) {
        int b = batch[r];
        if (b != cur) {
            atomicAdd(&gsum[cur * DD + 2 * lane], acc.x);
            atomicAdd(&gsum[cur * DD + 2 * lane + 1], acc.y);
            acc.x = 0.0f; acc.y = 0.0f;
            cur = b;
        }
        unsigned int v = h2[(unsigned int)r * 64u + lane];
        acc.x += bflo(v);
        acc.y += bfhi(v);
    }
    atomicAdd(&gsum[cur * DD + 2 * lane], acc.x);
    atomicAdd(&gsum[cur * DD + 2 * lane + 1], acc.y);
}

// ---------------- final head: inline graph-boundary binary search ----------------
__global__ __launch_bounds__(256) void final_k(const float* __restrict__ gsum, const int* __restrict__ batch,
                                               const float* __restrict__ Wlin, const float* __restrict__ blin,
                                               float* __restrict__ out) {
    int idx = blockIdx.x * 256 + threadIdx.x;
    if (idx >= NG * NC) return;
    int g = idx / NC, c = idx % NC;
    int s0, s1;
    {
        int lo = 0, hi = NN;
        while (lo < hi) { int m = (lo + hi) >> 1; if (batch[m] < g) lo = m + 1; else hi = m; }
        s0 = lo;
        lo = s0; hi = NN;
        while (lo < hi) { int m = (lo + hi) >> 1; if (batch[m] < g + 1) lo = m + 1; else hi = m; }
        s1 = lo;
    }
    int cnt = s1 - s0;
    float inv = 1.0f / fmaxf((float)cnt, 1.0f);
    float acc = blin[c];
    for (int k = 0; k < DD; ++k) acc = fmaf(gsum[g * DD + k] * inv, Wlin[k * NC + c], acc);
    out[idx] = acc;
}

extern "C" void kernel_launch(void* const* d_in, const int* in_sizes, int n_in,
                              void* d_out, int out_size, void* d_ws, size_t ws_size,
                              hipStream_t stream) {
    const float* x     = (const float*)d_in[0];
    const int*   ei    = (const int*)d_in[1];   // [2][NE]: row=src, col=dst
    const int*   batch = (const int*)d_in[2];
    const float* W1    = (const float*)d_in[3];
    const float* b1    = (const float*)d_in[4];
    const float* W2    = (const float*)d_in[5];
    const float* b2    = (const float*)d_in[6];
    const float* Wlin  = (const float*)d_in[7];
    const float* blin  = (const float*)d_in[8];
    float* out = (float*)d_out;

    const int* erow = ei;
    const int* ecol = ei + NE;

    char* ws = (char*)d_ws;
    size_t off = 0;
    auto alloc = [&](size_t bytes) {
        void* p = ws + off;
        off = (off + bytes + 255) & ~(size_t)255;
        return p;
    };
    unsigned short* hbuf  = (unsigned short*)alloc((size_t)NN * DD * 2);  // gemm out h (bf16, unscaled)
    unsigned short* habuf = (unsigned short*)alloc((size_t)NN * DD * 2);  // agg out (bf16)
    float* dinv     = (float*)alloc(NN * 4);
    int*   offs     = (int*)alloc((NN + 1) * 4);
    int*   bbase    = (int*)alloc((NB1 + 1) * 4);
    int*   hist     = (int*)alloc((size_t)NB1 * NWG1 * 4);
    int*   tmpe     = (int*)alloc((size_t)NE * 4);
    unsigned int* csrsrc = (unsigned int*)alloc((size_t)NE * 4);
    float* gsum     = (float*)alloc(NG * DD * 4);
    (void)ws_size; (void)in_sizes; (void)n_in; (void)out_size;

    // K1: hist + gsum-zero + gemm1 concurrently (gemm1 no longer needs dinv)
    k1_fused<<<NWG1 + 1 + GEMM_BLOCKS, 256, 0, stream>>>(ecol, hist, x, W1, hbuf, gsum);
    btot_k<<<1, 512, 0, stream>>>(hist, bbase);
    histscan_k<<<NB1, 256, 0, stream>>>(bbase, hist);
    part1_k<<<NWG1, 256, 0, stream>>>(erow, ecol, hist, tmpe);
    part2b_k<<<NB1, 512, 0, stream>>>(bbase, tmpe, csrsrc, offs, dinv);

    // layer 1 aggregate: hbuf -> habuf
    agg_k<<<NN / 8, 256, 0, stream>>>((const unsigned int*)hbuf, dinv, offs, csrsrc, b1, habuf);
    // layer 2: habuf -> hbuf (gemm) -> habuf (agg)
    gemm2_k<<<GEMM_BLOCKS, 256, 0, stream>>>(habuf, W2, hbuf);
    agg_k<<<NN / 8, 256, 0, stream>>>((const unsigned int*)hbuf, dinv, offs, csrsrc, b2, habuf);

    // pooling + head
    pool2_k<<<POOL_WAVES / 4, 256, 0, stream>>>(habuf, batch, gsum);
    final_k<<<(NG * NC + 255) / 256, 256, 0, stream>>>(gsum, batch, Wlin, blin, out);
}

// Round 14
// 265.665 us; speedup vs baseline: 1.0505x; 1.0505x over previous
//
#include <hip/hip_runtime.h>

#define NN 100000
#define NE 1600000
#define DD 128
#define NG 128
#define NC 10
#define AGG_WAVES 8192
#define POOL_WAVES 2048

#define B1SH 8                        // coarse bucket = 256 nodes
#define NB1 ((NN + 255) / 256)        // 391 buckets
#define EPB 8192                      // edges per partition block
#define NWG1 ((NE + EPB - 1) / EPB)   // 196 partition blocks
#define GEMM_BLOCKS ((NN + 63) / 64)  // 1563

typedef __attribute__((ext_vector_type(8))) short short8v;   // 8 bf16 (4 VGPRs)
typedef __attribute__((ext_vector_type(4))) float f32x4;     // MFMA acc

// fp32 -> bf16 round-to-nearest-even
__device__ __forceinline__ unsigned short f2bf(float f) {
    unsigned int u = __float_as_uint(f);
    u = (u + 0x7fffu + ((u >> 16) & 1u)) >> 16;
    return (unsigned short)u;
}
__device__ __forceinline__ float bflo(unsigned int p) { return __uint_as_float(p << 16); }
__device__ __forceinline__ float bfhi(unsigned int p) { return __uint_as_float(p & 0xffff0000u); }

// ---------------- radix partition P1a: per-(wg,bucket) histogram ----------------
__global__ __launch_bounds__(256) void hist_k(const int* __restrict__ col, int* __restrict__ hist) {
    __shared__ int lh[NB1];
    int t = threadIdx.x, w = blockIdx.x;
    for (int i = t; i < NB1; i += 256) lh[i] = 0;
    __syncthreads();
    int base = w * EPB;
    int lim = min(base + EPB, NE);
#pragma unroll 4
    for (int e = base + t; e < lim; e += 256) atomicAdd(&lh[col[e] >> B1SH], 1);
    __syncthreads();
    for (int i = t; i < NB1; i += 256) hist[i * NWG1 + w] = lh[i];
}

// ---------------- bucket totals + exclusive scan -> bbase (one block) ----------------
__global__ __launch_bounds__(512) void btot_k(const int* __restrict__ hist, int* __restrict__ bbase) {
    __shared__ int tmp[512];
    int t = threadIdx.x;
    int s = 0;
    if (t < NB1) {
        const int* hp = hist + t * NWG1;
        for (int w = 0; w < NWG1; ++w) s += hp[w];
    }
    tmp[t] = s;
    __syncthreads();
    for (int o = 1; o < 512; o <<= 1) {
        int v = (t >= o) ? tmp[t - o] : 0;
        __syncthreads();
        tmp[t] += v;
        __syncthreads();
    }
    if (t < NB1) bbase[t] = tmp[t] - s;
    if (t == 511) bbase[NB1] = tmp[511];  // == NE
}

// ---------------- per-bucket exclusive scan over wgs, seeded by bbase[b] ----------------
__global__ __launch_bounds__(256) void histscan_k(const int* __restrict__ bbase, int* __restrict__ hist) {
    __shared__ int tmp[256];
    int b = blockIdx.x, t = threadIdx.x;
    int v = (t < NWG1) ? hist[b * NWG1 + t] : 0;
    tmp[t] = v;
    __syncthreads();
    for (int o = 1; o < 256; o <<= 1) {
        int u = (t >= o) ? tmp[t - o] : 0;
        __syncthreads();
        tmp[t] += u;
        __syncthreads();
    }
    int excl = tmp[t] - v;
    if (t < NWG1) hist[b * NWG1 + t] = bbase[b] + excl;
}

// ---------------- partition edges into coarse-bucket segments (packed) ----------------
__global__ __launch_bounds__(256) void part1_k(const int* __restrict__ row, const int* __restrict__ col,
                                               const int* __restrict__ hist, int* __restrict__ tmpe) {
    __shared__ int lcur[NB1];
    int t = threadIdx.x, w = blockIdx.x;
    for (int i = t; i < NB1; i += 256) lcur[i] = hist[i * NWG1 + w];
    __syncthreads();
    int base = w * EPB;
    int lim = min(base + EPB, NE);
#pragma unroll 4
    for (int e = base + t; e < lim; e += 256) {
        int c = col[e];
        int pos = atomicAdd(&lcur[c >> B1SH], 1);
        tmpe[pos] = (row[e] << B1SH) | (c & 255);  // src<2^17 -> 25 bits
    }
}

// ---------------- P2: count local degrees, write offs+dinv, scatter to exact CSR ----------------
// csr_src stores src*64 (uint-index into the 2-bf16-per-uint row array)
__global__ __launch_bounds__(512) void part2b_k(const int* __restrict__ bbase, const int* __restrict__ tmpe,
                                                unsigned int* __restrict__ csr_src, int* __restrict__ offs,
                                                float* __restrict__ dinv) {
    __shared__ int lcnt[256];
    __shared__ int lsc[256];
    int b = blockIdx.x, t = threadIdx.x;
    if (t < 256) lcnt[t] = 0;
    __syncthreads();
    int ebeg = bbase[b], eend = bbase[b + 1];
    for (int e = ebeg + t; e < eend; e += 512) atomicAdd(&lcnt[tmpe[e] & 255], 1);
    __syncthreads();
    if (t < 256) lsc[t] = lcnt[t];
    __syncthreads();
    for (int o = 1; o < 256; o <<= 1) {
        int v = (t < 256 && t >= o) ? lsc[t - o] : 0;
        __syncthreads();
        if (t < 256) lsc[t] += v;
        __syncthreads();
    }
    int n0 = b << B1SH;
    if (t < 256) {
        int node = n0 + t;
        if (node < NN) {
            int excl = lsc[t] - lcnt[t];
            offs[node] = ebeg + excl;
            dinv[node] = rsqrtf((float)lcnt[t] + 1.0f);  // +1 self-loop
        }
    }
    if (b == NB1 - 1 && t == 0) offs[NN] = NE;
    __syncthreads();
    if (t < 256) lsc[t] = ebeg + (lsc[t] - lcnt[t]);  // cursors
    __syncthreads();
    for (int e = ebeg + t; e < eend; e += 512) {
        int p = tmpe[e];
        int pos = atomicAdd(&lsc[p & 255], 1);
        csr_src[pos] = (unsigned int)(p >> B1SH) << 6;  // src*64
    }
}

// ---------------- W pack (blocks 0,1) + gsum zero (block 2) ----------------
// frag(n, kk, lane, j): k = kk*32 + (lane>>4)*8 + j, col = n*16 + (lane&15)
__global__ __launch_bounds__(256) void pack_w2_k(const float* __restrict__ W1, const float* __restrict__ W2,
                                                 unsigned short* __restrict__ Wpk1,
                                                 unsigned short* __restrict__ Wpk2,
                                                 float* __restrict__ gsum) {
    int t = threadIdx.x;
    if (blockIdx.x == 2) {
        float4* g4 = (float4*)gsum;
        for (int i = t; i < NG * DD / 4; i += 256) g4[i] = make_float4(0, 0, 0, 0);
        return;
    }
    const float* W = blockIdx.x ? W2 : W1;
    unsigned short* Wpk = blockIdx.x ? Wpk2 : Wpk1;
    for (int f = t * 64; f < t * 64 + 64; ++f) {
        int j = f & 7, lane = (f >> 3) & 63, kk = (f >> 9) & 3, n = f >> 11;
        int k = kk * 32 + ((lane >> 4) << 3) + j;
        int c = n * 16 + (lane & 15);
        Wpk[f] = f2bf(W[k * DD + c]);
    }
}

// ---------------- MFMA GEMM: outb[r][:] = bf16( dinv[r] * (X[r][:] @ W) ) ----------------
template <int IN_BF16>
__global__ __launch_bounds__(256) void gemm_mfma_k(const void* __restrict__ Xv,
                                                   const unsigned short* __restrict__ Wpk,
                                                   const float* __restrict__ dinv,
                                                   unsigned short* __restrict__ outb) {
    __shared__ unsigned short wlds[16384];  // 32 KB
    int tid = threadIdx.x;
    const uint4* wg = (const uint4*)Wpk;
    uint4* wl = (uint4*)wlds;
#pragma unroll
    for (int i = 0; i < 8; ++i) wl[tid + i * 256] = wg[tid + i * 256];
    __syncthreads();

    int w = tid >> 6, lane = tid & 63;
    int kg = lane >> 4;  // 0..3
    int rowbase = blockIdx.x * 64 + w * 16;
    int rl = min(rowbase + (lane & 15), NN - 1);

    short8v a[4];
    if (IN_BF16) {
        const unsigned short* xb = (const unsigned short*)Xv;
#pragma unroll
        for (int kk = 0; kk < 4; ++kk)
            a[kk] = *(const short8v*)(xb + (long)rl * DD + kk * 32 + kg * 8);
    } else {
        const float* xf = (const float*)Xv;
#pragma unroll
        for (int kk = 0; kk < 4; ++kk) {
            float4 f0 = *(const float4*)(xf + (long)rl * DD + kk * 32 + kg * 8);
            float4 f1 = *(const float4*)(xf + (long)rl * DD + kk * 32 + kg * 8 + 4);
            short8v t;
            t[0] = (short)f2bf(f0.x); t[1] = (short)f2bf(f0.y);
            t[2] = (short)f2bf(f0.z); t[3] = (short)f2bf(f0.w);
            t[4] = (short)f2bf(f1.x); t[5] = (short)f2bf(f1.y);
            t[6] = (short)f2bf(f1.z); t[7] = (short)f2bf(f1.w);
            a[kk] = t;
        }
    }

    f32x4 acc[8];
#pragma unroll
    for (int n = 0; n < 8; ++n) acc[n] = (f32x4){0.f, 0.f, 0.f, 0.f};
#pragma unroll
    for (int n = 0; n < 8; ++n) {
#pragma unroll
        for (int kk = 0; kk < 4; ++kk) {
            short8v b = *(const short8v*)(wlds + ((n * 4 + kk) * 64 + lane) * 8);
            acc[n] = __builtin_amdgcn_mfma_f32_16x16x32_bf16(a[kk], b, acc[n], 0, 0, 0);
        }
    }

    // D: col = n*16 + (lane&15), row = rowbase + kg*4 + reg
    int c0 = lane & 15;
#pragma unroll
    for (int reg = 0; reg < 4; ++reg) {
        int row = rowbase + kg * 4 + reg;
        if (row < NN) {
            float dv = dinv[row];
            unsigned short* op = outb + (long)row * DD + c0;
#pragma unroll
            for (int n = 0; n < 8; ++n) op[n * 16] = f2bf(dv * acc[n][reg]);
        }
    }
}

// ---------------- aggregation: grid-strided wave per node, bf16 gather, fp32 acc ----------------
// h' is dinv-scaled; out[i] = relu(dinv[i]*(sum h'[src] + h'[i]) + b)
__global__ __launch_bounds__(256) void agg_k(const unsigned int* __restrict__ hpb,
                                             const float* __restrict__ dinv,
                                             const int* __restrict__ offs,
                                             const unsigned int* __restrict__ csr,
                                             const float* __restrict__ bias,
                                             unsigned short* __restrict__ outb) {
    int wv = (blockIdx.x << 2) + (threadIdx.x >> 6);
    unsigned int lane = threadIdx.x & 63;
    float2 bb = ((const float2*)bias)[lane];
    for (int node = wv; node < NN; node += AGG_WAVES) {
        int s = offs[node];
        int e_end = offs[node + 1];
        unsigned int ps = hpb[(unsigned int)node * 64u + lane];  // self-loop
        float accx = bflo(ps);
        float accy = bfhi(ps);
        int e = s;
        for (; e + 8 <= e_end; e += 8) {
            unsigned int p0 = hpb[csr[e] + lane];
            unsigned int p1 = hpb[csr[e + 1] + lane];
            unsigned int p2 = hpb[csr[e + 2] + lane];
            unsigned int p3 = hpb[csr[e + 3] + lane];
            unsigned int p4 = hpb[csr[e + 4] + lane];
            unsigned int p5 = hpb[csr[e + 5] + lane];
            unsigned int p6 = hpb[csr[e + 6] + lane];
            unsigned int p7 = hpb[csr[e + 7] + lane];
            accx += (bflo(p0) + bflo(p1)) + (bflo(p2) + bflo(p3)) +
                    (bflo(p4) + bflo(p5)) + (bflo(p6) + bflo(p7));
            accy += (bfhi(p0) + bfhi(p1)) + (bfhi(p2) + bfhi(p3)) +
                    (bfhi(p4) + bfhi(p5)) + (bfhi(p6) + bfhi(p7));
        }
        if (e + 4 <= e_end) {
            unsigned int p0 = hpb[csr[e] + lane];
            unsigned int p1 = hpb[csr[e + 1] + lane];
            unsigned int p2 = hpb[csr[e + 2] + lane];
            unsigned int p3 = hpb[csr[e + 3] + lane];
            accx += (bflo(p0) + bflo(p1)) + (bflo(p2) + bflo(p3));
            accy += (bfhi(p0) + bfhi(p1)) + (bfhi(p2) + bfhi(p3));
            e += 4;
        }
        for (; e < e_end; ++e) {
            unsigned int p0 = hpb[csr[e] + lane];
            accx += bflo(p0);
            accy += bfhi(p0);
        }
        float dv = dinv[node];
        float ox = fmaxf(fmaf(dv, accx, bb.x), 0.0f);
        float oy = fmaxf(fmaf(dv, accy, bb.y), 0.0f);
        ((ushort2*)outb)[(unsigned int)node * 64u + lane] = make_ushort2(f2bf(ox), f2bf(oy));
    }
}

// ---------------- pooling: 2048 waves over sorted batch (bf16 in), boundary-flush atomics ------
__global__ __launch_bounds__(256) void pool2_k(const unsigned short* __restrict__ h,
                                               const int* __restrict__ batch,
                                               float* __restrict__ gsum) {
    int wave = (blockIdx.x * 256 + threadIdx.x) >> 6;
    int lane = threadIdx.x & 63;
    const int per = (NN + POOL_WAVES - 1) / POOL_WAVES;  // 49
    int s = wave * per;
    int e = min(s + per, NN);
    if (s >= e) return;
    const unsigned int* h2 = (const unsigned int*)h;
    float2 acc = {0.0f, 0.0f};
    int cur = batch[s];
    for (int r = s; r < e; ++r) {
        int b = batch[r];
        if (b != cur) {
            atomicAdd(&gsum[cur * DD + 2 * lane], acc.x);
            atomicAdd(&gsum[cur * DD + 2 * lane + 1], acc.y);
            acc.x = 0.0f; acc.y = 0.0f;
            cur = b;
        }
        unsigned int v = h2[(unsigned int)r * 64u + lane];
        acc.x += bflo(v);
        acc.y += bfhi(v);
    }
    atomicAdd(&gsum[cur * DD + 2 * lane], acc.x);
    atomicAdd(&gsum[cur * DD + 2 * lane + 1], acc.y);
}

// ---------------- final head: inline graph-boundary binary search ----------------
__global__ __launch_bounds__(256) void final_k(const float* __restrict__ gsum, const int* __restrict__ batch,
                                               const float* __restrict__ Wlin, const float* __restrict__ blin,
                                               float* __restrict__ out) {
    int idx = blockIdx.x * 256 + threadIdx.x;
    if (idx >= NG * NC) return;
    int g = idx / NC, c = idx % NC;
    int s0, s1;
    {
        int lo = 0, hi = NN;
        while (lo < hi) { int m = (lo + hi) >> 1; if (batch[m] < g) lo = m + 1; else hi = m; }
        s0 = lo;
        lo = s0; hi = NN;
        while (lo < hi) { int m = (lo + hi) >> 1; if (batch[m] < g + 1) lo = m + 1; else hi = m; }
        s1 = lo;
    }
    int cnt = s1 - s0;
    float inv = 1.0f / fmaxf((float)cnt, 1.0f);
    float acc = blin[c];
    for (int k = 0; k < DD; ++k) acc = fmaf(gsum[g * DD + k] * inv, Wlin[k * NC + c], acc);
    out[idx] = acc;
}

extern "C" void kernel_launch(void* const* d_in, const int* in_sizes, int n_in,
                              void* d_out, int out_size, void* d_ws, size_t ws_size,
                              hipStream_t stream) {
    const float* x     = (const float*)d_in[0];
    const int*   ei    = (const int*)d_in[1];   // [2][NE]: row=src, col=dst
    const int*   batch = (const int*)d_in[2];
    const float* W1    = (const float*)d_in[3];
    const float* b1    = (const float*)d_in[4];
    const float* W2    = (const float*)d_in[5];
    const float* b2    = (const float*)d_in[6];
    const float* Wlin  = (const float*)d_in[7];
    const float* blin  = (const float*)d_in[8];
    float* out = (float*)d_out;

    const int* erow = ei;
    const int* ecol = ei + NE;

    char* ws = (char*)d_ws;
    size_t off = 0;
    auto alloc = [&](size_t bytes) {
        void* p = ws + off;
        off = (off + bytes + 255) & ~(size_t)255;
        return p;
    };
    unsigned short* hbuf  = (unsigned short*)alloc((size_t)NN * DD * 2);  // gemm out h' (bf16, scaled)
    unsigned short* habuf = (unsigned short*)alloc((size_t)NN * DD * 2);  // agg out (bf16)
    unsigned short* Wpk1  = (unsigned short*)alloc(16384 * 2);
    unsigned short* Wpk2  = (unsigned short*)alloc(16384 * 2);
    float* dinv     = (float*)alloc(NN * 4);
    int*   offs     = (int*)alloc((NN + 1) * 4);
    int*   bbase    = (int*)alloc((NB1 + 1) * 4);
    int*   hist     = (int*)alloc((size_t)NB1 * NWG1 * 4);
    int*   tmpe     = (int*)alloc((size_t)NE * 4);
    unsigned int* csrsrc = (unsigned int*)alloc((size_t)NE * 4);
    float* gsum     = (float*)alloc(NG * DD * 4);
    (void)ws_size; (void)in_sizes; (void)n_in; (void)out_size;

    pack_w2_k<<<3, 256, 0, stream>>>(W1, W2, Wpk1, Wpk2, gsum);
    hist_k<<<NWG1, 256, 0, stream>>>(ecol, hist);
    btot_k<<<1, 512, 0, stream>>>(hist, bbase);
    histscan_k<<<NB1, 256, 0, stream>>>(bbase, hist);
    part1_k<<<NWG1, 256, 0, stream>>>(erow, ecol, hist, tmpe);
    part2b_k<<<NB1, 512, 0, stream>>>(bbase, tmpe, csrsrc, offs, dinv);

    // layer 1: x (fp32) -> hbuf (bf16 h') -> habuf (bf16 agg+relu)
    gemm_mfma_k<0><<<GEMM_BLOCKS, 256, 0, stream>>>(x, Wpk1, dinv, hbuf);
    agg_k<<<AGG_WAVES / 4, 256, 0, stream>>>((const unsigned int*)hbuf, dinv, offs, csrsrc, b1, habuf);
    // layer 2: habuf (bf16) -> hbuf (bf16 h') -> habuf (bf16 agg+relu)
    gemm_mfma_k<1><<<GEMM_BLOCKS, 256, 0, stream>>>(habuf, Wpk2, dinv, hbuf);
    agg_k<<<AGG_WAVES / 4, 256, 0, stream>>>((const unsigned int*)hbuf, dinv, offs, csrsrc, b2, habuf);

    // pooling + head
    pool2_k<<<POOL_WAVES / 4, 256, 0, stream>>>(habuf, batch, gsum);
    final_k<<<(NG * NC + 255) / 256, 256, 0, stream>>>(gsum, batch, Wlin, blin, out);
}

// Round 15
// 243.558 us; speedup vs baseline: 1.1458x; 1.0908x over previous
//
#include <hip/hip_runtime.h>

#define NN 100000
#define NE 1600000
#define DD 128
#define NG 128
#define NC 10
#define AGG_WAVES 8192

#define B1SH 8                        // coarse bucket = 256 nodes
#define NB1 ((NN + 255) / 256)        // 391 buckets
#define EPB 8192                      // edges per partition block
#define NWG1 ((NE + EPB - 1) / EPB)   // 196 partition blocks
#define GEMM_BLOCKS ((NN + 63) / 64)  // 1563

typedef __attribute__((ext_vector_type(8))) short short8v;   // 8 bf16 (4 VGPRs)
typedef __attribute__((ext_vector_type(4))) float f32x4;     // MFMA acc

// fp32 -> bf16 round-to-nearest-even
__device__ __forceinline__ unsigned short f2bf(float f) {
    unsigned int u = __float_as_uint(f);
    u = (u + 0x7fffu + ((u >> 16) & 1u)) >> 16;
    return (unsigned short)u;
}
__device__ __forceinline__ float bflo(unsigned int p) { return __uint_as_float(p << 16); }
__device__ __forceinline__ float bfhi(unsigned int p) { return __uint_as_float(p & 0xffff0000u); }

// ---------------- GEMM body (prepacked W staged to LDS): outb = bf16(dinv * (X @ W)) ----------
template <int IN_BF16>
__device__ __forceinline__ void gemm_body(const void* __restrict__ Xv,
                                          const unsigned short* __restrict__ Wpk,
                                          const float* __restrict__ dinv,
                                          unsigned short* __restrict__ outb, int blk,
                                          unsigned short* wlds) {
    int tid = threadIdx.x;
    const uint4* wg = (const uint4*)Wpk;
    uint4* wl = (uint4*)wlds;
#pragma unroll
    for (int i = 0; i < 8; ++i) wl[tid + i * 256] = wg[tid + i * 256];
    __syncthreads();

    int w = tid >> 6, lane = tid & 63;
    int kg = lane >> 4;  // 0..3
    int rowbase = blk * 64 + w * 16;
    int rl = min(rowbase + (lane & 15), NN - 1);

    short8v a[4];
    if (IN_BF16) {
        const unsigned short* xb = (const unsigned short*)Xv;
#pragma unroll
        for (int kk = 0; kk < 4; ++kk)
            a[kk] = *(const short8v*)(xb + (long)rl * DD + kk * 32 + kg * 8);
    } else {
        const float* xf = (const float*)Xv;
#pragma unroll
        for (int kk = 0; kk < 4; ++kk) {
            float4 f0 = *(const float4*)(xf + (long)rl * DD + kk * 32 + kg * 8);
            float4 f1 = *(const float4*)(xf + (long)rl * DD + kk * 32 + kg * 8 + 4);
            short8v t;
            t[0] = (short)f2bf(f0.x); t[1] = (short)f2bf(f0.y);
            t[2] = (short)f2bf(f0.z); t[3] = (short)f2bf(f0.w);
            t[4] = (short)f2bf(f1.x); t[5] = (short)f2bf(f1.y);
            t[6] = (short)f2bf(f1.z); t[7] = (short)f2bf(f1.w);
            a[kk] = t;
        }
    }

    f32x4 acc[8];
#pragma unroll
    for (int n = 0; n < 8; ++n) acc[n] = (f32x4){0.f, 0.f, 0.f, 0.f};
#pragma unroll
    for (int n = 0; n < 8; ++n) {
#pragma unroll
        for (int kk = 0; kk < 4; ++kk) {
            short8v b = *(const short8v*)(wlds + ((n * 4 + kk) * 64 + lane) * 8);
            acc[n] = __builtin_amdgcn_mfma_f32_16x16x32_bf16(a[kk], b, acc[n], 0, 0, 0);
        }
    }

    // D: col = n*16 + (lane&15), row = rowbase + kg*4 + reg
    int c0 = lane & 15;
#pragma unroll
    for (int reg = 0; reg < 4; ++reg) {
        int row = rowbase + kg * 4 + reg;
        if (row < NN) {
            float dv = dinv[row];
            unsigned short* op = outb + (long)row * DD + c0;
#pragma unroll
            for (int n = 0; n < 8; ++n) op[n * 16] = f2bf(dv * acc[n][reg]);
        }
    }
}

// ---------------- K1 fat kernel: hist (blocks 0..NWG1-1) | gemm1 (rest) ----------------
// NOTE: gemm1 writes h' = dinv*(xW1); dinv for gemm1 is NOT yet computed when K1 runs...
// -> gemm1 here writes UNSCALED? No: keep R14 semantics by having gemm1 not need dinv:
//    we fold dinv into agg's self-term and gather? That failed (R13). Instead gemm1 uses
//    dinv produced by part2b — so gemm1 CANNOT run before part2b.
// Resolution: K1's gemm blocks compute and stash bf16(xW1) UNSCALED into hbuf; agg1 then
// needs dinv[src]*h[src] (two streams — R13 regression). To avoid that, scale1_k below
// rescales hbuf in-place (streaming 25.6MB read+write ≈ 9µs) after part2b. Net still wins
// vs serial gemm1 (~15µs + gap) and keeps agg single-stream.
__global__ __launch_bounds__(256) void k1_fused(const int* __restrict__ col, int* __restrict__ hist,
                                                const float* __restrict__ x,
                                                const unsigned short* __restrict__ Wpk1,
                                                unsigned short* __restrict__ hbuf) {
    __shared__ unsigned short wlds[16384];  // 32 KB (hist aliases as int*)
    int bid = blockIdx.x, t = threadIdx.x;
    if (bid < NWG1) {
        int* lh = (int*)wlds;
        for (int i = t; i < NB1; i += 256) lh[i] = 0;
        __syncthreads();
        int base = bid * EPB;
        int lim = min(base + EPB, NE);
#pragma unroll 4
        for (int e = base + t; e < lim; e += 256) atomicAdd(&lh[col[e] >> B1SH], 1);
        __syncthreads();
        for (int i = t; i < NB1; i += 256) hist[i * NWG1 + bid] = lh[i];
    } else {
        // gemm1 unscaled: pass dinv=nullptr-like via all-ones? Use scale in separate pass.
        int tid = threadIdx.x;
        const uint4* wg = (const uint4*)Wpk1;
        uint4* wl = (uint4*)wlds;
#pragma unroll
        for (int i = 0; i < 8; ++i) wl[tid + i * 256] = wg[tid + i * 256];
        __syncthreads();
        int w = tid >> 6, lane = tid & 63;
        int kg = lane >> 4;
        int blk = bid - NWG1;
        int rowbase = blk * 64 + w * 16;
        int rl = min(rowbase + (lane & 15), NN - 1);
        short8v a[4];
        const float* xf = x;
#pragma unroll
        for (int kk = 0; kk < 4; ++kk) {
            float4 f0 = *(const float4*)(xf + (long)rl * DD + kk * 32 + kg * 8);
            float4 f1 = *(const float4*)(xf + (long)rl * DD + kk * 32 + kg * 8 + 4);
            short8v tv;
            tv[0] = (short)f2bf(f0.x); tv[1] = (short)f2bf(f0.y);
            tv[2] = (short)f2bf(f0.z); tv[3] = (short)f2bf(f0.w);
            tv[4] = (short)f2bf(f1.x); tv[5] = (short)f2bf(f1.y);
            tv[6] = (short)f2bf(f1.z); tv[7] = (short)f2bf(f1.w);
            a[kk] = tv;
        }
        f32x4 acc[8];
#pragma unroll
        for (int n = 0; n < 8; ++n) acc[n] = (f32x4){0.f, 0.f, 0.f, 0.f};
#pragma unroll
        for (int n = 0; n < 8; ++n) {
#pragma unroll
            for (int kk = 0; kk < 4; ++kk) {
                short8v b = *(const short8v*)(wlds + ((n * 4 + kk) * 64 + lane) * 8);
                acc[n] = __builtin_amdgcn_mfma_f32_16x16x32_bf16(a[kk], b, acc[n], 0, 0, 0);
            }
        }
        int c0 = lane & 15;
#pragma unroll
        for (int reg = 0; reg < 4; ++reg) {
            int row = rowbase + kg * 4 + reg;
            if (row < NN) {
                unsigned short* op = hbuf + (long)row * DD + c0;
#pragma unroll
                for (int n = 0; n < 8; ++n) op[n * 16] = f2bf(acc[n][reg]);
            }
        }
    }
}

// ---------------- scale hbuf in-place by dinv[row] (bf16, vectorized) ----------------
__global__ __launch_bounds__(256) void scale1_k(unsigned int* __restrict__ hpb,
                                                const float* __restrict__ dinv) {
    int wv = (blockIdx.x << 2) + (threadIdx.x >> 6);  // wave = row
    unsigned int lane = threadIdx.x & 63;
    for (int row = wv; row < NN; row += AGG_WAVES) {
        float dv = dinv[row];
        unsigned int p = hpb[(unsigned int)row * 64u + lane];
        hpb[(unsigned int)row * 64u + lane] =
            ((unsigned int)f2bf(dv * bflo(p))) | ((unsigned int)f2bf(dv * bfhi(p)) << 16);
    }
}

// ---------------- bucket totals + exclusive scan -> bbase (one block) ----------------
__global__ __launch_bounds__(512) void btot_k(const int* __restrict__ hist, int* __restrict__ bbase) {
    __shared__ int tmp[512];
    int t = threadIdx.x;
    int s = 0;
    if (t < NB1) {
        const int* hp = hist + t * NWG1;
        for (int w = 0; w < NWG1; ++w) s += hp[w];
    }
    tmp[t] = s;
    __syncthreads();
    for (int o = 1; o < 512; o <<= 1) {
        int v = (t >= o) ? tmp[t - o] : 0;
        __syncthreads();
        tmp[t] += v;
        __syncthreads();
    }
    if (t < NB1) bbase[t] = tmp[t] - s;
    if (t == 511) bbase[NB1] = tmp[511];  // == NE
}

// ---------------- per-bucket exclusive scan over wgs, seeded by bbase[b] ----------------
__global__ __launch_bounds__(256) void histscan_k(const int* __restrict__ bbase, int* __restrict__ hist) {
    __shared__ int tmp[256];
    int b = blockIdx.x, t = threadIdx.x;
    int v = (t < NWG1) ? hist[b * NWG1 + t] : 0;
    tmp[t] = v;
    __syncthreads();
    for (int o = 1; o < 256; o <<= 1) {
        int u = (t >= o) ? tmp[t - o] : 0;
        __syncthreads();
        tmp[t] += u;
        __syncthreads();
    }
    int excl = tmp[t] - v;
    if (t < NWG1) hist[b * NWG1 + t] = bbase[b] + excl;
}

// ---------------- partition edges into coarse-bucket segments (packed) ----------------
__global__ __launch_bounds__(256) void part1_k(const int* __restrict__ row, const int* __restrict__ col,
                                               const int* __restrict__ hist, int* __restrict__ tmpe) {
    __shared__ int lcur[NB1];
    int t = threadIdx.x, w = blockIdx.x;
    for (int i = t; i < NB1; i += 256) lcur[i] = hist[i * NWG1 + w];
    __syncthreads();
    int base = w * EPB;
    int lim = min(base + EPB, NE);
#pragma unroll 4
    for (int e = base + t; e < lim; e += 256) {
        int c = col[e];
        int pos = atomicAdd(&lcur[c >> B1SH], 1);
        tmpe[pos] = (row[e] << B1SH) | (c & 255);  // src<2^17 -> 25 bits
    }
}

// ---------------- P2: count local degrees, write offs+dinv, scatter to exact CSR ----------------
__global__ __launch_bounds__(512) void part2b_k(const int* __restrict__ bbase, const int* __restrict__ tmpe,
                                                unsigned int* __restrict__ csr_src, int* __restrict__ offs,
                                                float* __restrict__ dinv) {
    __shared__ int lcnt[256];
    __shared__ int lsc[256];
    int b = blockIdx.x, t = threadIdx.x;
    if (t < 256) lcnt[t] = 0;
    __syncthreads();
    int ebeg = bbase[b], eend = bbase[b + 1];
    for (int e = ebeg + t; e < eend; e += 512) atomicAdd(&lcnt[tmpe[e] & 255], 1);
    __syncthreads();
    if (t < 256) lsc[t] = lcnt[t];
    __syncthreads();
    for (int o = 1; o < 256; o <<= 1) {
        int v = (t < 256 && t >= o) ? lsc[t - o] : 0;
        __syncthreads();
        if (t < 256) lsc[t] += v;
        __syncthreads();
    }
    int n0 = b << B1SH;
    if (t < 256) {
        int node = n0 + t;
        if (node < NN) {
            int excl = lsc[t] - lcnt[t];
            offs[node] = ebeg + excl;
            dinv[node] = rsqrtf((float)lcnt[t] + 1.0f);  // +1 self-loop
        }
    }
    if (b == NB1 - 1 && t == 0) offs[NN] = NE;
    __syncthreads();
    if (t < 256) lsc[t] = ebeg + (lsc[t] - lcnt[t]);  // cursors
    __syncthreads();
    for (int e = ebeg + t; e < eend; e += 512) {
        int p = tmpe[e];
        int pos = atomicAdd(&lsc[p & 255], 1);
        csr_src[pos] = (unsigned int)(p >> B1SH) << 6;  // src*64
    }
}

// ---------------- W pack (blocks 0,1) + gsum zero (block 2) ----------------
__global__ __launch_bounds__(256) void pack_w2_k(const float* __restrict__ W1, const float* __restrict__ W2,
                                                 unsigned short* __restrict__ Wpk1,
                                                 unsigned short* __restrict__ Wpk2,
                                                 float* __restrict__ gsum) {
    int t = threadIdx.x;
    if (blockIdx.x == 2) {
        float4* g4 = (float4*)gsum;
        for (int i = t; i < NG * DD / 4; i += 256) g4[i] = make_float4(0, 0, 0, 0);
        return;
    }
    const float* W = blockIdx.x ? W2 : W1;
    unsigned short* Wpk = blockIdx.x ? Wpk2 : Wpk1;
    for (int f = t * 64; f < t * 64 + 64; ++f) {
        int j = f & 7, lane = (f >> 3) & 63, kk = (f >> 9) & 3, n = f >> 11;
        int k = kk * 32 + ((lane >> 4) << 3) + j;
        int c = n * 16 + (lane & 15);
        Wpk[f] = f2bf(W[k * DD + c]);
    }
}

__global__ __launch_bounds__(256) void gemm2_k(const unsigned short* __restrict__ xb,
                                               const unsigned short* __restrict__ Wpk,
                                               const float* __restrict__ dinv,
                                               unsigned short* __restrict__ outb) {
    __shared__ unsigned short wlds[16384];
    gemm_body<1>(xb, Wpk, dinv, outb, blockIdx.x, wlds);
}

// ---------------- agg edge-sum macro body ----------------
__device__ __forceinline__ void agg_node(const unsigned int* __restrict__ hpb,
                                         const unsigned int* __restrict__ csr,
                                         int s, int e_end, unsigned int lane,
                                         float& accx, float& accy) {
    int e = s;
    for (; e + 8 <= e_end; e += 8) {
        unsigned int p0 = hpb[csr[e] + lane];
        unsigned int p1 = hpb[csr[e + 1] + lane];
        unsigned int p2 = hpb[csr[e + 2] + lane];
        unsigned int p3 = hpb[csr[e + 3] + lane];
        unsigned int p4 = hpb[csr[e + 4] + lane];
        unsigned int p5 = hpb[csr[e + 5] + lane];
        unsigned int p6 = hpb[csr[e + 6] + lane];
        unsigned int p7 = hpb[csr[e + 7] + lane];
        accx += (bflo(p0) + bflo(p1)) + (bflo(p2) + bflo(p3)) +
                (bflo(p4) + bflo(p5)) + (bflo(p6) + bflo(p7));
        accy += (bfhi(p0) + bfhi(p1)) + (bfhi(p2) + bfhi(p3)) +
                (bfhi(p4) + bfhi(p5)) + (bfhi(p6) + bfhi(p7));
    }
    if (e + 4 <= e_end) {
        unsigned int p0 = hpb[csr[e] + lane];
        unsigned int p1 = hpb[csr[e + 1] + lane];
        unsigned int p2 = hpb[csr[e + 2] + lane];
        unsigned int p3 = hpb[csr[e + 3] + lane];
        accx += (bflo(p0) + bflo(p1)) + (bflo(p2) + bflo(p3));
        accy += (bfhi(p0) + bfhi(p1)) + (bfhi(p2) + bfhi(p3));
        e += 4;
    }
    for (; e < e_end; ++e) {
        unsigned int p0 = hpb[csr[e] + lane];
        accx += bflo(p0);
        accy += bfhi(p0);
    }
}

// ---------------- agg1: grid-strided wave per node -> bf16 habuf ----------------
__global__ __launch_bounds__(256) void agg_k(const unsigned int* __restrict__ hpb,
                                             const float* __restrict__ dinv,
                                             const int* __restrict__ offs,
                                             const unsigned int* __restrict__ csr,
                                             const float* __restrict__ bias,
                                             unsigned short* __restrict__ outb) {
    int wv = (blockIdx.x << 2) + (threadIdx.x >> 6);
    unsigned int lane = threadIdx.x & 63;
    float2 bb = ((const float2*)bias)[lane];
    for (int node = wv; node < NN; node += AGG_WAVES) {
        unsigned int ps = hpb[(unsigned int)node * 64u + lane];
        float accx = bflo(ps), accy = bfhi(ps);
        agg_node(hpb, csr, offs[node], offs[node + 1], lane, accx, accy);
        float dv = dinv[node];
        float ox = fmaxf(fmaf(dv, accx, bb.x), 0.0f);
        float oy = fmaxf(fmaf(dv, accy, bb.y), 0.0f);
        ((ushort2*)outb)[(unsigned int)node * 64u + lane] = make_ushort2(f2bf(ox), f2bf(oy));
    }
}

// ---------------- agg2+pool: contiguous node range per wave, boundary-flush into gsum ----------
__global__ __launch_bounds__(256) void agg2pool_k(const unsigned int* __restrict__ hpb,
                                                  const float* __restrict__ dinv,
                                                  const int* __restrict__ offs,
                                                  const unsigned int* __restrict__ csr,
                                                  const float* __restrict__ bias,
                                                  const int* __restrict__ batch,
                                                  float* __restrict__ gsum) {
    int wave = (blockIdx.x << 2) + (threadIdx.x >> 6);
    unsigned int lane = threadIdx.x & 63;
    const int per = (NN + AGG_WAVES - 1) / AGG_WAVES;  // 13
    int s = wave * per;
    int e = min(s + per, NN);
    if (s >= e) return;
    float2 bb = ((const float2*)bias)[lane];
    float2 acc = {0.0f, 0.0f};
    int cur = batch[s];
    for (int node = s; node < e; ++node) {
        int bg = batch[node];
        if (bg != cur) {
            atomicAdd(&gsum[cur * DD + 2 * lane], acc.x);
            atomicAdd(&gsum[cur * DD + 2 * lane + 1], acc.y);
            acc.x = 0.0f; acc.y = 0.0f;
            cur = bg;
        }
        unsigned int ps = hpb[(unsigned int)node * 64u + lane];
        float accx = bflo(ps), accy = bfhi(ps);
        agg_node(hpb, csr, offs[node], offs[node + 1], lane, accx, accy);
        float dv = dinv[node];
        acc.x += fmaxf(fmaf(dv, accx, bb.x), 0.0f);
        acc.y += fmaxf(fmaf(dv, accy, bb.y), 0.0f);
    }
    atomicAdd(&gsum[cur * DD + 2 * lane], acc.x);
    atomicAdd(&gsum[cur * DD + 2 * lane + 1], acc.y);
}

// ---------------- final head: inline graph-boundary binary search ----------------
__global__ __launch_bounds__(256) void final_k(const float* __restrict__ gsum, const int* __restrict__ batch,
                                               const float* __restrict__ Wlin, const float* __restrict__ blin,
                                               float* __restrict__ out) {
    int idx = blockIdx.x * 256 + threadIdx.x;
    if (idx >= NG * NC) return;
    int g = idx / NC, c = idx % NC;
    int s0, s1;
    {
        int lo = 0, hi = NN;
        while (lo < hi) { int m = (lo + hi) >> 1; if (batch[m] < g) lo = m + 1; else hi = m; }
        s0 = lo;
        lo = s0; hi = NN;
        while (lo < hi) { int m = (lo + hi) >> 1; if (batch[m] < g + 1) lo = m + 1; else hi = m; }
        s1 = lo;
    }
    int cnt = s1 - s0;
    float inv = 1.0f / fmaxf((float)cnt, 1.0f);
    float acc = blin[c];
    for (int k = 0; k < DD; ++k) acc = fmaf(gsum[g * DD + k] * inv, Wlin[k * NC + c], acc);
    out[idx] = acc;
}

extern "C" void kernel_launch(void* const* d_in, const int* in_sizes, int n_in,
                              void* d_out, int out_size, void* d_ws, size_t ws_size,
                              hipStream_t stream) {
    const float* x     = (const float*)d_in[0];
    const int*   ei    = (const int*)d_in[1];   // [2][NE]: row=src, col=dst
    const int*   batch = (const int*)d_in[2];
    const float* W1    = (const float*)d_in[3];
    const float* b1    = (const float*)d_in[4];
    const float* W2    = (const float*)d_in[5];
    const float* b2    = (const float*)d_in[6];
    const float* Wlin  = (const float*)d_in[7];
    const float* blin  = (const float*)d_in[8];
    float* out = (float*)d_out;

    const int* erow = ei;
    const int* ecol = ei + NE;

    char* ws = (char*)d_ws;
    size_t off = 0;
    auto alloc = [&](size_t bytes) {
        void* p = ws + off;
        off = (off + bytes + 255) & ~(size_t)255;
        return p;
    };
    unsigned short* hbuf  = (unsigned short*)alloc((size_t)NN * DD * 2);  // h (bf16)
    unsigned short* habuf = (unsigned short*)alloc((size_t)NN * DD * 2);  // agg1 out (bf16)
    unsigned short* Wpk1  = (unsigned short*)alloc(16384 * 2);
    unsigned short* Wpk2  = (unsigned short*)alloc(16384 * 2);
    float* dinv     = (float*)alloc(NN * 4);
    int*   offs     = (int*)alloc((NN + 1) * 4);
    int*   bbase    = (int*)alloc((NB1 + 1) * 4);
    int*   hist     = (int*)alloc((size_t)NB1 * NWG1 * 4);
    int*   tmpe     = (int*)alloc((size_t)NE * 4);
    unsigned int* csrsrc = (unsigned int*)alloc((size_t)NE * 4);
    float* gsum     = (float*)alloc(NG * DD * 4);
    (void)ws_size; (void)in_sizes; (void)n_in; (void)out_size;

    pack_w2_k<<<3, 256, 0, stream>>>(W1, W2, Wpk1, Wpk2, gsum);
    // K1: hist + gemm1(unscaled) concurrently
    k1_fused<<<NWG1 + GEMM_BLOCKS, 256, 0, stream>>>(ecol, hist, x, Wpk1, hbuf);
    btot_k<<<1, 512, 0, stream>>>(hist, bbase);
    histscan_k<<<NB1, 256, 0, stream>>>(bbase, hist);
    part1_k<<<NWG1, 256, 0, stream>>>(erow, ecol, hist, tmpe);
    part2b_k<<<NB1, 512, 0, stream>>>(bbase, tmpe, csrsrc, offs, dinv);
    // apply dinv scaling to h (streaming, in-place)
    scale1_k<<<AGG_WAVES / 4, 256, 0, stream>>>((unsigned int*)hbuf, dinv);

    // layer 1 aggregate: hbuf -> habuf
    agg_k<<<AGG_WAVES / 4, 256, 0, stream>>>((const unsigned int*)hbuf, dinv, offs, csrsrc, b1, habuf);
    // layer 2: habuf -> hbuf (gemm, dinv-scaled) -> gsum (agg+relu+pool fused)
    gemm2_k<<<GEMM_BLOCKS, 256, 0, stream>>>(habuf, Wpk2, dinv, hbuf);
    agg2pool_k<<<AGG_WAVES / 4, 256, 0, stream>>>((const unsigned int*)hbuf, dinv, offs, csrsrc, b2,
                                                  batch, gsum);
    final_k<<<(NG * NC + 255) / 256, 256, 0, stream>>>(gsum, batch, Wlin, blin, out);
}

// Round 16
// 240.800 us; speedup vs baseline: 1.1589x; 1.0115x over previous
//
#include <hip/hip_runtime.h>

#define NN 100000
#define NE 1600000
#define DD 128
#define NG 128
#define NC 10
#define AGG_WAVES 8192

#define B1SH 8                        // coarse bucket = 256 nodes
#define NB1 ((NN + 255) / 256)        // 391 buckets
#define EPB 8192                      // edges per partition block
#define NWG1 ((NE + EPB - 1) / EPB)   // 196 partition blocks
#define GEMM_BLOCKS ((NN + 63) / 64)  // 1563

typedef __attribute__((ext_vector_type(8))) short short8v;   // 8 bf16 (4 VGPRs)
typedef __attribute__((ext_vector_type(4))) float f32x4;     // MFMA acc

// fp32 -> bf16 round-to-nearest-even
__device__ __forceinline__ unsigned short f2bf(float f) {
    unsigned int u = __float_as_uint(f);
    u = (u + 0x7fffu + ((u >> 16) & 1u)) >> 16;
    return (unsigned short)u;
}
__device__ __forceinline__ float bflo(unsigned int p) { return __uint_as_float(p << 16); }
__device__ __forceinline__ float bfhi(unsigned int p) { return __uint_as_float(p & 0xffff0000u); }

// ---------------- GEMM body (prepacked W staged to LDS): outb = bf16(dinv * (X @ W)) ----------
template <int IN_BF16>
__device__ __forceinline__ void gemm_body(const void* __restrict__ Xv,
                                          const unsigned short* __restrict__ Wpk,
                                          const float* __restrict__ dinv,
                                          unsigned short* __restrict__ outb, int blk,
                                          unsigned short* wlds) {
    int tid = threadIdx.x;
    const uint4* wg = (const uint4*)Wpk;
    uint4* wl = (uint4*)wlds;
#pragma unroll
    for (int i = 0; i < 8; ++i) wl[tid + i * 256] = wg[tid + i * 256];
    __syncthreads();

    int w = tid >> 6, lane = tid & 63;
    int kg = lane >> 4;  // 0..3
    int rowbase = blk * 64 + w * 16;
    int rl = min(rowbase + (lane & 15), NN - 1);

    short8v a[4];
    if (IN_BF16) {
        const unsigned short* xb = (const unsigned short*)Xv;
#pragma unroll
        for (int kk = 0; kk < 4; ++kk)
            a[kk] = *(const short8v*)(xb + (long)rl * DD + kk * 32 + kg * 8);
    } else {
        const float* xf = (const float*)Xv;
#pragma unroll
        for (int kk = 0; kk < 4; ++kk) {
            float4 f0 = *(const float4*)(xf + (long)rl * DD + kk * 32 + kg * 8);
            float4 f1 = *(const float4*)(xf + (long)rl * DD + kk * 32 + kg * 8 + 4);
            short8v t;
            t[0] = (short)f2bf(f0.x); t[1] = (short)f2bf(f0.y);
            t[2] = (short)f2bf(f0.z); t[3] = (short)f2bf(f0.w);
            t[4] = (short)f2bf(f1.x); t[5] = (short)f2bf(f1.y);
            t[6] = (short)f2bf(f1.z); t[7] = (short)f2bf(f1.w);
            a[kk] = t;
        }
    }

    f32x4 acc[8];
#pragma unroll
    for (int n = 0; n < 8; ++n) acc[n] = (f32x4){0.f, 0.f, 0.f, 0.f};
#pragma unroll
    for (int n = 0; n < 8; ++n) {
#pragma unroll
        for (int kk = 0; kk < 4; ++kk) {
            short8v b = *(const short8v*)(wlds + ((n * 4 + kk) * 64 + lane) * 8);
            acc[n] = __builtin_amdgcn_mfma_f32_16x16x32_bf16(a[kk], b, acc[n], 0, 0, 0);
        }
    }

    // D: col = n*16 + (lane&15), row = rowbase + kg*4 + reg
    int c0 = lane & 15;
#pragma unroll
    for (int reg = 0; reg < 4; ++reg) {
        int row = rowbase + kg * 4 + reg;
        if (row < NN) {
            float dv = dinv[row];
            unsigned short* op = outb + (long)row * DD + c0;
#pragma unroll
            for (int n = 0; n < 8; ++n) op[n * 16] = f2bf(dv * acc[n][reg]);
        }
    }
}

// ---------------- K1 fat kernel: hist (blocks 0..NWG1-1) | gemm1 unscaled (rest) ----------------
__global__ __launch_bounds__(256) void k1_fused(const int* __restrict__ col, int* __restrict__ hist,
                                                const float* __restrict__ x,
                                                const unsigned short* __restrict__ Wpk1,
                                                unsigned short* __restrict__ hbuf) {
    __shared__ unsigned short wlds[16384];  // 32 KB (hist aliases as int*)
    int bid = blockIdx.x, t = threadIdx.x;
    if (bid < NWG1) {
        int* lh = (int*)wlds;
        for (int i = t; i < NB1; i += 256) lh[i] = 0;
        __syncthreads();
        int base = bid * EPB;
        int lim = min(base + EPB, NE);
#pragma unroll 4
        for (int e = base + t; e < lim; e += 256) atomicAdd(&lh[col[e] >> B1SH], 1);
        __syncthreads();
        for (int i = t; i < NB1; i += 256) hist[i * NWG1 + bid] = lh[i];
    } else {
        int tid = threadIdx.x;
        const uint4* wg = (const uint4*)Wpk1;
        uint4* wl = (uint4*)wlds;
#pragma unroll
        for (int i = 0; i < 8; ++i) wl[tid + i * 256] = wg[tid + i * 256];
        __syncthreads();
        int w = tid >> 6, lane = tid & 63;
        int kg = lane >> 4;
        int blk = bid - NWG1;
        int rowbase = blk * 64 + w * 16;
        int rl = min(rowbase + (lane & 15), NN - 1);
        short8v a[4];
        const float* xf = x;
#pragma unroll
        for (int kk = 0; kk < 4; ++kk) {
            float4 f0 = *(const float4*)(xf + (long)rl * DD + kk * 32 + kg * 8);
            float4 f1 = *(const float4*)(xf + (long)rl * DD + kk * 32 + kg * 8 + 4);
            short8v tv;
            tv[0] = (short)f2bf(f0.x); tv[1] = (short)f2bf(f0.y);
            tv[2] = (short)f2bf(f0.z); tv[3] = (short)f2bf(f0.w);
            tv[4] = (short)f2bf(f1.x); tv[5] = (short)f2bf(f1.y);
            tv[6] = (short)f2bf(f1.z); tv[7] = (short)f2bf(f1.w);
            a[kk] = tv;
        }
        f32x4 acc[8];
#pragma unroll
        for (int n = 0; n < 8; ++n) acc[n] = (f32x4){0.f, 0.f, 0.f, 0.f};
#pragma unroll
        for (int n = 0; n < 8; ++n) {
#pragma unroll
            for (int kk = 0; kk < 4; ++kk) {
                short8v b = *(const short8v*)(wlds + ((n * 4 + kk) * 64 + lane) * 8);
                acc[n] = __builtin_amdgcn_mfma_f32_16x16x32_bf16(a[kk], b, acc[n], 0, 0, 0);
            }
        }
        int c0 = lane & 15;
#pragma unroll
        for (int reg = 0; reg < 4; ++reg) {
            int row = rowbase + kg * 4 + reg;
            if (row < NN) {
                unsigned short* op = hbuf + (long)row * DD + c0;
#pragma unroll
                for (int n = 0; n < 8; ++n) op[n * 16] = f2bf(acc[n][reg]);
            }
        }
    }
}

// ---------------- bucket totals + exclusive scan -> bbase (one block) ----------------
__global__ __launch_bounds__(512) void btot_k(const int* __restrict__ hist, int* __restrict__ bbase) {
    __shared__ int tmp[512];
    int t = threadIdx.x;
    int s = 0;
    if (t < NB1) {
        const int* hp = hist + t * NWG1;
        for (int w = 0; w < NWG1; ++w) s += hp[w];
    }
    tmp[t] = s;
    __syncthreads();
    for (int o = 1; o < 512; o <<= 1) {
        int v = (t >= o) ? tmp[t - o] : 0;
        __syncthreads();
        tmp[t] += v;
        __syncthreads();
    }
    if (t < NB1) bbase[t] = tmp[t] - s;
    if (t == 511) bbase[NB1] = tmp[511];  // == NE
}

// ---------------- per-bucket exclusive scan over wgs, seeded by bbase[b] ----------------
__global__ __launch_bounds__(256) void histscan_k(const int* __restrict__ bbase, int* __restrict__ hist) {
    __shared__ int tmp[256];
    int b = blockIdx.x, t = threadIdx.x;
    int v = (t < NWG1) ? hist[b * NWG1 + t] : 0;
    tmp[t] = v;
    __syncthreads();
    for (int o = 1; o < 256; o <<= 1) {
        int u = (t >= o) ? tmp[t - o] : 0;
        __syncthreads();
        tmp[t] += u;
        __syncthreads();
    }
    int excl = tmp[t] - v;
    if (t < NWG1) hist[b * NWG1 + t] = bbase[b] + excl;
}

// ---------------- partition edges into coarse-bucket segments (packed) ----------------
__global__ __launch_bounds__(256) void part1_k(const int* __restrict__ row, const int* __restrict__ col,
                                               const int* __restrict__ hist, int* __restrict__ tmpe) {
    __shared__ int lcur[NB1];
    int t = threadIdx.x, w = blockIdx.x;
    for (int i = t; i < NB1; i += 256) lcur[i] = hist[i * NWG1 + w];
    __syncthreads();
    int base = w * EPB;
    int lim = min(base + EPB, NE);
#pragma unroll 4
    for (int e = base + t; e < lim; e += 256) {
        int c = col[e];
        int pos = atomicAdd(&lcur[c >> B1SH], 1);
        tmpe[pos] = (row[e] << B1SH) | (c & 255);  // src<2^17 -> 25 bits
    }
}

// ---------------- P2: degrees -> offs+dinv, scatter exact CSR, then scale own hbuf rows -------
__global__ __launch_bounds__(512) void part2b_k(const int* __restrict__ bbase, const int* __restrict__ tmpe,
                                                unsigned int* __restrict__ csr_src, int* __restrict__ offs,
                                                float* __restrict__ dinv, unsigned int* __restrict__ hpb) {
    __shared__ int lcnt[256];
    __shared__ int lsc[256];
    int b = blockIdx.x, t = threadIdx.x;
    if (t < 256) lcnt[t] = 0;
    __syncthreads();
    int ebeg = bbase[b], eend = bbase[b + 1];
    for (int e = ebeg + t; e < eend; e += 512) atomicAdd(&lcnt[tmpe[e] & 255], 1);
    __syncthreads();
    if (t < 256) lsc[t] = lcnt[t];
    __syncthreads();
    for (int o = 1; o < 256; o <<= 1) {
        int v = (t < 256 && t >= o) ? lsc[t - o] : 0;
        __syncthreads();
        if (t < 256) lsc[t] += v;
        __syncthreads();
    }
    int n0 = b << B1SH;
    if (t < 256) {
        int c = lcnt[t];
        int excl = lsc[t] - c;
        int node = n0 + t;
        float dvf = rsqrtf((float)c + 1.0f);  // +1 self-loop
        if (node < NN) {
            offs[node] = ebeg + excl;
            dinv[node] = dvf;
        }
        lsc[t] = ebeg + excl;          // cursor
        ((float*)lcnt)[t] = dvf;       // stash dinv for scale tail (lcnt no longer needed)
    }
    if (b == NB1 - 1 && t == 0) offs[NN] = NE;
    __syncthreads();
    for (int e = ebeg + t; e < eend; e += 512) {
        int p = tmpe[e];
        int pos = atomicAdd(&lsc[p & 255], 1);
        csr_src[pos] = (unsigned int)(p >> B1SH) << 6;  // src*64
    }
    // scale this block's 256 hbuf rows in place by dinv (h -> h')
    int nend = min(n0 + 256, NN);
    unsigned int lane = t & 63;
    for (int r = n0 + (t >> 6); r < nend; r += 8) {
        float dv = ((const float*)lcnt)[r - n0];
        unsigned int p = hpb[(unsigned int)r * 64u + lane];
        hpb[(unsigned int)r * 64u + lane] =
            ((unsigned int)f2bf(dv * bflo(p))) | ((unsigned int)f2bf(dv * bfhi(p)) << 16);
    }
}

// ---------------- W pack (blocks 0,1) + gsum zero (block 2) ----------------
__global__ __launch_bounds__(256) void pack_w2_k(const float* __restrict__ W1, const float* __restrict__ W2,
                                                 unsigned short* __restrict__ Wpk1,
                                                 unsigned short* __restrict__ Wpk2,
                                                 float* __restrict__ gsum) {
    int t = threadIdx.x;
    if (blockIdx.x == 2) {
        float4* g4 = (float4*)gsum;
        for (int i = t; i < NG * DD / 4; i += 256) g4[i] = make_float4(0, 0, 0, 0);
        return;
    }
    const float* W = blockIdx.x ? W2 : W1;
    unsigned short* Wpk = blockIdx.x ? Wpk2 : Wpk1;
    for (int f = t * 64; f < t * 64 + 64; ++f) {
        int j = f & 7, lane = (f >> 3) & 63, kk = (f >> 9) & 3, n = f >> 11;
        int k = kk * 32 + ((lane >> 4) << 3) + j;
        int c = n * 16 + (lane & 15);
        Wpk[f] = f2bf(W[k * DD + c]);
    }
}

__global__ __launch_bounds__(256) void gemm2_k(const unsigned short* __restrict__ xb,
                                               const unsigned short* __restrict__ Wpk,
                                               const float* __restrict__ dinv,
                                               unsigned short* __restrict__ outb) {
    __shared__ unsigned short wlds[16384];
    gemm_body<1>(xb, Wpk, dinv, outb, blockIdx.x, wlds);
}

// ---------------- agg edge-sum body: 16/8/4/1 unroll ladder ----------------
__device__ __forceinline__ void agg_node(const unsigned int* __restrict__ hpb,
                                         const unsigned int* __restrict__ csr,
                                         int s, int e_end, unsigned int lane,
                                         float& accx, float& accy) {
    int e = s;
    for (; e + 16 <= e_end; e += 16) {
        unsigned int p0 = hpb[csr[e] + lane];
        unsigned int p1 = hpb[csr[e + 1] + lane];
        unsigned int p2 = hpb[csr[e + 2] + lane];
        unsigned int p3 = hpb[csr[e + 3] + lane];
        unsigned int p4 = hpb[csr[e + 4] + lane];
        unsigned int p5 = hpb[csr[e + 5] + lane];
        unsigned int p6 = hpb[csr[e + 6] + lane];
        unsigned int p7 = hpb[csr[e + 7] + lane];
        unsigned int q0 = hpb[csr[e + 8] + lane];
        unsigned int q1 = hpb[csr[e + 9] + lane];
        unsigned int q2 = hpb[csr[e + 10] + lane];
        unsigned int q3 = hpb[csr[e + 11] + lane];
        unsigned int q4 = hpb[csr[e + 12] + lane];
        unsigned int q5 = hpb[csr[e + 13] + lane];
        unsigned int q6 = hpb[csr[e + 14] + lane];
        unsigned int q7 = hpb[csr[e + 15] + lane];
        accx += ((bflo(p0) + bflo(p1)) + (bflo(p2) + bflo(p3))) +
                ((bflo(p4) + bflo(p5)) + (bflo(p6) + bflo(p7))) +
                ((bflo(q0) + bflo(q1)) + (bflo(q2) + bflo(q3))) +
                ((bflo(q4) + bflo(q5)) + (bflo(q6) + bflo(q7)));
        accy += ((bfhi(p0) + bfhi(p1)) + (bfhi(p2) + bfhi(p3))) +
                ((bfhi(p4) + bfhi(p5)) + (bfhi(p6) + bfhi(p7))) +
                ((bfhi(q0) + bfhi(q1)) + (bfhi(q2) + bfhi(q3))) +
                ((bfhi(q4) + bfhi(q5)) + (bfhi(q6) + bfhi(q7)));
    }
    if (e + 8 <= e_end) {
        unsigned int p0 = hpb[csr[e] + lane];
        unsigned int p1 = hpb[csr[e + 1] + lane];
        unsigned int p2 = hpb[csr[e + 2] + lane];
        unsigned int p3 = hpb[csr[e + 3] + lane];
        unsigned int p4 = hpb[csr[e + 4] + lane];
        unsigned int p5 = hpb[csr[e + 5] + lane];
        unsigned int p6 = hpb[csr[e + 6] + lane];
        unsigned int p7 = hpb[csr[e + 7] + lane];
        accx += (bflo(p0) + bflo(p1)) + (bflo(p2) + bflo(p3)) +
                (bflo(p4) + bflo(p5)) + (bflo(p6) + bflo(p7));
        accy += (bfhi(p0) + bfhi(p1)) + (bfhi(p2) + bfhi(p3)) +
                (bfhi(p4) + bfhi(p5)) + (bfhi(p6) + bfhi(p7));
        e += 8;
    }
    if (e + 4 <= e_end) {
        unsigned int p0 = hpb[csr[e] + lane];
        unsigned int p1 = hpb[csr[e + 1] + lane];
        unsigned int p2 = hpb[csr[e + 2] + lane];
        unsigned int p3 = hpb[csr[e + 3] + lane];
        accx += (bflo(p0) + bflo(p1)) + (bflo(p2) + bflo(p3));
        accy += (bfhi(p0) + bfhi(p1)) + (bfhi(p2) + bfhi(p3));
        e += 4;
    }
    for (; e < e_end; ++e) {
        unsigned int p0 = hpb[csr[e] + lane];
        accx += bflo(p0);
        accy += bfhi(p0);
    }
}

// ---------------- agg1: grid-strided wave per node -> bf16 habuf ----------------
__global__ __launch_bounds__(256) void agg_k(const unsigned int* __restrict__ hpb,
                                             const float* __restrict__ dinv,
                                             const int* __restrict__ offs,
                                             const unsigned int* __restrict__ csr,
                                             const float* __restrict__ bias,
                                             unsigned short* __restrict__ outb) {
    int wv = (blockIdx.x << 2) + (threadIdx.x >> 6);
    unsigned int lane = threadIdx.x & 63;
    float2 bb = ((const float2*)bias)[lane];
    for (int node = wv; node < NN; node += AGG_WAVES) {
        unsigned int ps = hpb[(unsigned int)node * 64u + lane];
        float accx = bflo(ps), accy = bfhi(ps);
        agg_node(hpb, csr, offs[node], offs[node + 1], lane, accx, accy);
        float dv = dinv[node];
        float ox = fmaxf(fmaf(dv, accx, bb.x), 0.0f);
        float oy = fmaxf(fmaf(dv, accy, bb.y), 0.0f);
        ((ushort2*)outb)[(unsigned int)node * 64u + lane] = make_ushort2(f2bf(ox), f2bf(oy));
    }
}

// ---------------- agg2+pool: contiguous node range per wave, boundary-flush into gsum ----------
__global__ __launch_bounds__(256) void agg2pool_k(const unsigned int* __restrict__ hpb,
                                                  const float* __restrict__ dinv,
                                                  const int* __restrict__ offs,
                                                  const unsigned int* __restrict__ csr,
                                                  const float* __restrict__ bias,
                                                  const int* __restrict__ batch,
                                                  float* __restrict__ gsum) {
    int wave = (blockIdx.x << 2) + (threadIdx.x >> 6);
    unsigned int lane = threadIdx.x & 63;
    const int per = (NN + AGG_WAVES - 1) / AGG_WAVES;  // 13
    int s = wave * per;
    int e = min(s + per, NN);
    if (s >= e) return;
    float2 bb = ((const float2*)bias)[lane];
    float2 acc = {0.0f, 0.0f};
    int cur = batch[s];
    for (int node = s; node < e; ++node) {
        int bg = batch[node];
        if (bg != cur) {
            atomicAdd(&gsum[cur * DD + 2 * lane], acc.x);
            atomicAdd(&gsum[cur * DD + 2 * lane + 1], acc.y);
            acc.x = 0.0f; acc.y = 0.0f;
            cur = bg;
        }
        unsigned int ps = hpb[(unsigned int)node * 64u + lane];
        float accx = bflo(ps), accy = bfhi(ps);
        agg_node(hpb, csr, offs[node], offs[node + 1], lane, accx, accy);
        float dv = dinv[node];
        acc.x += fmaxf(fmaf(dv, accx, bb.x), 0.0f);
        acc.y += fmaxf(fmaf(dv, accy, bb.y), 0.0f);
    }
    atomicAdd(&gsum[cur * DD + 2 * lane], acc.x);
    atomicAdd(&gsum[cur * DD + 2 * lane + 1], acc.y);
}

// ---------------- final head: inline graph-boundary binary search ----------------
__global__ __launch_bounds__(256) void final_k(const float* __restrict__ gsum, const int* __restrict__ batch,
                                               const float* __restrict__ Wlin, const float* __restrict__ blin,
                                               float* __restrict__ out) {
    int idx = blockIdx.x * 256 + threadIdx.x;
    if (idx >= NG * NC) return;
    int g = idx / NC, c = idx % NC;
    int s0, s1;
    {
        int lo = 0, hi = NN;
        while (lo < hi) { int m = (lo + hi) >> 1; if (batch[m] < g) lo = m + 1; else hi = m; }
        s0 = lo;
        lo = s0; hi = NN;
        while (lo < hi) { int m = (lo + hi) >> 1; if (batch[m] < g + 1) lo = m + 1; else hi = m; }
        s1 = lo;
    }
    int cnt = s1 - s0;
    float inv = 1.0f / fmaxf((float)cnt, 1.0f);
    float acc = blin[c];
    for (int k = 0; k < DD; ++k) acc = fmaf(gsum[g * DD + k] * inv, Wlin[k * NC + c], acc);
    out[idx] = acc;
}

extern "C" void kernel_launch(void* const* d_in, const int* in_sizes, int n_in,
                              void* d_out, int out_size, void* d_ws, size_t ws_size,
                              hipStream_t stream) {
    const float* x     = (const float*)d_in[0];
    const int*   ei    = (const int*)d_in[1];   // [2][NE]: row=src, col=dst
    const int*   batch = (const int*)d_in[2];
    const float* W1    = (const float*)d_in[3];
    const float* b1    = (const float*)d_in[4];
    const float* W2    = (const float*)d_in[5];
    const float* b2    = (const float*)d_in[6];
    const float* Wlin  = (const float*)d_in[7];
    const float* blin  = (const float*)d_in[8];
    float* out = (float*)d_out;

    const int* erow = ei;
    const int* ecol = ei + NE;

    char* ws = (char*)d_ws;
    size_t off = 0;
    auto alloc = [&](size_t bytes) {
        void* p = ws + off;
        off = (off + bytes + 255) & ~(size_t)255;
        return p;
    };
    unsigned short* hbuf  = (unsigned short*)alloc((size_t)NN * DD * 2);  // h / h' (bf16)
    unsigned short* habuf = (unsigned short*)alloc((size_t)NN * DD * 2);  // agg1 out (bf16)
    unsigned short* Wpk1  = (unsigned short*)alloc(16384 * 2);
    unsigned short* Wpk2  = (unsigned short*)alloc(16384 * 2);
    float* dinv     = (float*)alloc(NN * 4);
    int*   offs     = (int*)alloc((NN + 1) * 4);
    int*   bbase    = (int*)alloc((NB1 + 1) * 4);
    int*   hist     = (int*)alloc((size_t)NB1 * NWG1 * 4);
    int*   tmpe     = (int*)alloc((size_t)NE * 4);
    unsigned int* csrsrc = (unsigned int*)alloc((size_t)NE * 4);
    float* gsum     = (float*)alloc(NG * DD * 4);
    (void)ws_size; (void)in_sizes; (void)n_in; (void)out_size;

    pack_w2_k<<<3, 256, 0, stream>>>(W1, W2, Wpk1, Wpk2, gsum);
    // K1: hist + gemm1(unscaled) concurrently
    k1_fused<<<NWG1 + GEMM_BLOCKS, 256, 0, stream>>>(ecol, hist, x, Wpk1, hbuf);
    btot_k<<<1, 512, 0, stream>>>(hist, bbase);
    histscan_k<<<NB1, 256, 0, stream>>>(bbase, hist);
    part1_k<<<NWG1, 256, 0, stream>>>(erow, ecol, hist, tmpe);
    // part2b: builds offs/dinv/csr AND applies dinv scaling to its own hbuf rows
    part2b_k<<<NB1, 512, 0, stream>>>(bbase, tmpe, csrsrc, offs, dinv, (unsigned int*)hbuf);

    // layer 1 aggregate: hbuf -> habuf
    agg_k<<<AGG_WAVES / 4, 256, 0, stream>>>((const unsigned int*)hbuf, dinv, offs, csrsrc, b1, habuf);
    // layer 2: habuf -> hbuf (gemm, dinv-scaled) -> gsum (agg+relu+pool fused)
    gemm2_k<<<GEMM_BLOCKS, 256, 0, stream>>>(habuf, Wpk2, dinv, hbuf);
    agg2pool_k<<<AGG_WAVES / 4, 256, 0, stream>>>((const unsigned int*)hbuf, dinv, offs, csrsrc, b2,
                                                  batch, gsum);
    final_k<<<(NG * NC + 255) / 256, 256, 0, stream>>>(gsum, batch, Wlin, blin, out);
}

// Round 17
// 231.656 us; speedup vs baseline: 1.2047x; 1.0395x over previous
//
#include <hip/hip_runtime.h>

#define NN 100000
#define NE 1600000
#define DD 128
#define NG 128
#define NC 10
#define AGG_WAVES 8192

#define B1SH 8                        // coarse bucket = 256 nodes
#define NB1 ((NN + 255) / 256)        // 391 buckets
#define EPB 8192                      // edges per partition block
#define NWG1 ((NE + EPB - 1) / EPB)   // 196 partition blocks
#define GEMM_BLOCKS ((NN + 63) / 64)  // 1563

typedef __attribute__((ext_vector_type(8))) short short8v;   // 8 bf16 (4 VGPRs)
typedef __attribute__((ext_vector_type(4))) float f32x4;     // MFMA acc

// fp32 -> bf16 round-to-nearest-even
__device__ __forceinline__ unsigned short f2bf(float f) {
    unsigned int u = __float_as_uint(f);
    u = (u + 0x7fffu + ((u >> 16) & 1u)) >> 16;
    return (unsigned short)u;
}
__device__ __forceinline__ float bflo(unsigned int p) { return __uint_as_float(p << 16); }
__device__ __forceinline__ float bfhi(unsigned int p) { return __uint_as_float(p & 0xffff0000u); }

// ---------------- gemm1 body: hbuf[r][:] = bf16( x[r][:] @ W1 )  (unscaled) ----------------
// frag(n, kk, lane, j): k = kk*32 + (lane>>4)*8 + j, col = n*16 + (lane&15)
__device__ __forceinline__ void gemm1_body(const float* __restrict__ x,
                                           const unsigned short* __restrict__ Wpk1,
                                           unsigned short* __restrict__ hbuf, int blk,
                                           unsigned short* wlds) {
    int tid = threadIdx.x;
    const uint4* wg = (const uint4*)Wpk1;
    uint4* wl = (uint4*)wlds;
#pragma unroll
    for (int i = 0; i < 8; ++i) wl[tid + i * 256] = wg[tid + i * 256];
    __syncthreads();
    int w = tid >> 6, lane = tid & 63;
    int kg = lane >> 4;
    int rowbase = blk * 64 + w * 16;
    int rl = min(rowbase + (lane & 15), NN - 1);
    short8v a[4];
#pragma unroll
    for (int kk = 0; kk < 4; ++kk) {
        float4 f0 = *(const float4*)(x + (long)rl * DD + kk * 32 + kg * 8);
        float4 f1 = *(const float4*)(x + (long)rl * DD + kk * 32 + kg * 8 + 4);
        short8v tv;
        tv[0] = (short)f2bf(f0.x); tv[1] = (short)f2bf(f0.y);
        tv[2] = (short)f2bf(f0.z); tv[3] = (short)f2bf(f0.w);
        tv[4] = (short)f2bf(f1.x); tv[5] = (short)f2bf(f1.y);
        tv[6] = (short)f2bf(f1.z); tv[7] = (short)f2bf(f1.w);
        a[kk] = tv;
    }
    f32x4 acc[8];
#pragma unroll
    for (int n = 0; n < 8; ++n) acc[n] = (f32x4){0.f, 0.f, 0.f, 0.f};
#pragma unroll
    for (int n = 0; n < 8; ++n) {
#pragma unroll
        for (int kk = 0; kk < 4; ++kk) {
            short8v b = *(const short8v*)(wlds + ((n * 4 + kk) * 64 + lane) * 8);
            acc[n] = __builtin_amdgcn_mfma_f32_16x16x32_bf16(a[kk], b, acc[n], 0, 0, 0);
        }
    }
    int c0 = lane & 15;
#pragma unroll
    for (int reg = 0; reg < 4; ++reg) {
        int row = rowbase + kg * 4 + reg;
        if (row < NN) {
            unsigned short* op = hbuf + (long)row * DD + c0;
#pragma unroll
            for (int n = 0; n < 8; ++n) op[n * 16] = f2bf(acc[n][reg]);
        }
    }
}

// ---------------- K0 fat: hist (0..NWG1-1) | pack W1 (NWG1) | pack W2 (NWG1+1) | zero (NWG1+2) --
__global__ __launch_bounds__(256) void k0_fused(const int* __restrict__ col, int* __restrict__ hist,
                                                const float* __restrict__ W1, const float* __restrict__ W2,
                                                unsigned short* __restrict__ Wpk1,
                                                unsigned short* __restrict__ Wpk2,
                                                float* __restrict__ gsum) {
    __shared__ int lh[NB1];
    int bid = blockIdx.x, t = threadIdx.x;
    if (bid < NWG1) {
        for (int i = t; i < NB1; i += 256) lh[i] = 0;
        __syncthreads();
        int base = bid * EPB;
        int lim = min(base + EPB, NE);
#pragma unroll 4
        for (int e = base + t; e < lim; e += 256) atomicAdd(&lh[col[e] >> B1SH], 1);
        __syncthreads();
        for (int i = t; i < NB1; i += 256) hist[i * NWG1 + bid] = lh[i];
    } else if (bid == NWG1 + 2) {
        float4* g4 = (float4*)gsum;
        for (int i = t; i < NG * DD / 4; i += 256) g4[i] = make_float4(0, 0, 0, 0);
    } else {
        const float* W = (bid == NWG1) ? W1 : W2;
        unsigned short* Wpk = (bid == NWG1) ? Wpk1 : Wpk2;
        for (int f = t * 64; f < t * 64 + 64; ++f) {
            int j = f & 7, lane = (f >> 3) & 63, kk = (f >> 9) & 3, n = f >> 11;
            int k = kk * 32 + ((lane >> 4) << 3) + j;
            int c = n * 16 + (lane & 15);
            Wpk[f] = f2bf(W[k * DD + c]);
        }
    }
}

// ---------------- bucket totals + exclusive scan -> bbase (one block) ----------------
__global__ __launch_bounds__(512) void btot_k(const int* __restrict__ hist, int* __restrict__ bbase) {
    __shared__ int tmp[512];
    int t = threadIdx.x;
    int s = 0;
    if (t < NB1) {
        const int* hp = hist + t * NWG1;
        for (int w = 0; w < NWG1; ++w) s += hp[w];
    }
    tmp[t] = s;
    __syncthreads();
    for (int o = 1; o < 512; o <<= 1) {
        int v = (t >= o) ? tmp[t - o] : 0;
        __syncthreads();
        tmp[t] += v;
        __syncthreads();
    }
    if (t < NB1) bbase[t] = tmp[t] - s;
    if (t == 511) bbase[NB1] = tmp[511];  // == NE
}

// ---------------- per-bucket exclusive scan over wgs, seeded by bbase[b] ----------------
__global__ __launch_bounds__(256) void histscan_k(const int* __restrict__ bbase, int* __restrict__ hist) {
    __shared__ int tmp[256];
    int b = blockIdx.x, t = threadIdx.x;
    int v = (t < NWG1) ? hist[b * NWG1 + t] : 0;
    tmp[t] = v;
    __syncthreads();
    for (int o = 1; o < 256; o <<= 1) {
        int u = (t >= o) ? tmp[t - o] : 0;
        __syncthreads();
        tmp[t] += u;
        __syncthreads();
    }
    int excl = tmp[t] - v;
    if (t < NWG1) hist[b * NWG1 + t] = bbase[b] + excl;
}

// ---------------- K3 fat: part1 (0..NWG1-1) | gemm1 (NWG1..) ----------------
__global__ __launch_bounds__(256) void k3_fused(const int* __restrict__ row, const int* __restrict__ col,
                                                const int* __restrict__ hist, int* __restrict__ tmpe,
                                                const float* __restrict__ x,
                                                const unsigned short* __restrict__ Wpk1,
                                                unsigned short* __restrict__ hbuf) {
    __shared__ unsigned short wlds[16384];  // 32 KB (part1 aliases int lcur[NB1])
    int bid = blockIdx.x, t = threadIdx.x;
    if (bid < NWG1) {
        int* lcur = (int*)wlds;
        for (int i = t; i < NB1; i += 256) lcur[i] = hist[i * NWG1 + bid];
        __syncthreads();
        int base = bid * EPB;
        int lim = min(base + EPB, NE);
#pragma unroll 4
        for (int e = base + t; e < lim; e += 256) {
            int c = col[e];
            int pos = atomicAdd(&lcur[c >> B1SH], 1);
            tmpe[pos] = (row[e] << B1SH) | (c & 255);  // src<2^17 -> 25 bits
        }
    } else {
        gemm1_body(x, Wpk1, hbuf, bid - NWG1, wlds);
    }
}

// ---------------- P2: degrees -> offs+dinv, scatter exact CSR, then scale own hbuf rows -------
__global__ __launch_bounds__(512) void part2b_k(const int* __restrict__ bbase, const int* __restrict__ tmpe,
                                                unsigned int* __restrict__ csr_src, int* __restrict__ offs,
                                                float* __restrict__ dinv, unsigned int* __restrict__ hpb) {
    __shared__ int lcnt[256];
    __shared__ int lsc[256];
    int b = blockIdx.x, t = threadIdx.x;
    if (t < 256) lcnt[t] = 0;
    __syncthreads();
    int ebeg = bbase[b], eend = bbase[b + 1];
    for (int e = ebeg + t; e < eend; e += 512) atomicAdd(&lcnt[tmpe[e] & 255], 1);
    __syncthreads();
    if (t < 256) lsc[t] = lcnt[t];
    __syncthreads();
    for (int o = 1; o < 256; o <<= 1) {
        int v = (t < 256 && t >= o) ? lsc[t - o] : 0;
        __syncthreads();
        if (t < 256) lsc[t] += v;
        __syncthreads();
    }
    int n0 = b << B1SH;
    if (t < 256) {
        int c = lcnt[t];
        int excl = lsc[t] - c;
        int node = n0 + t;
        float dvf = rsqrtf((float)c + 1.0f);  // +1 self-loop
        if (node < NN) {
            offs[node] = ebeg + excl;
            dinv[node] = dvf;
        }
        lsc[t] = ebeg + excl;          // cursor
        ((float*)lcnt)[t] = dvf;       // stash dinv for scale tail
    }
    if (b == NB1 - 1 && t == 0) offs[NN] = NE;
    __syncthreads();
    for (int e = ebeg + t; e < eend; e += 512) {
        int p = tmpe[e];
        int pos = atomicAdd(&lsc[p & 255], 1);
        csr_src[pos] = (unsigned int)(p >> B1SH) << 6;  // src*64
    }
    // scale this block's 256 hbuf rows in place by dinv (h -> h')
    int nend = min(n0 + 256, NN);
    unsigned int lane = t & 63;
    for (int r = n0 + (t >> 6); r < nend; r += 8) {
        float dv = ((const float*)lcnt)[r - n0];
        unsigned int p = hpb[(unsigned int)r * 64u + lane];
        hpb[(unsigned int)r * 64u + lane] =
            ((unsigned int)f2bf(dv * bflo(p))) | ((unsigned int)f2bf(dv * bfhi(p)) << 16);
    }
}

// ---------------- gemm2: habuf (bf16) @ W2, dinv-scaled output ----------------
__global__ __launch_bounds__(256) void gemm2_k(const unsigned short* __restrict__ xb,
                                               const unsigned short* __restrict__ Wpk,
                                               const float* __restrict__ dinv,
                                               unsigned short* __restrict__ outb) {
    __shared__ unsigned short wlds[16384];
    int tid = threadIdx.x;
    const uint4* wg = (const uint4*)Wpk;
    uint4* wl = (uint4*)wlds;
#pragma unroll
    for (int i = 0; i < 8; ++i) wl[tid + i * 256] = wg[tid + i * 256];
    __syncthreads();
    int w = tid >> 6, lane = tid & 63;
    int kg = lane >> 4;
    int rowbase = blockIdx.x * 64 + w * 16;
    int rl = min(rowbase + (lane & 15), NN - 1);
    short8v a[4];
#pragma unroll
    for (int kk = 0; kk < 4; ++kk)
        a[kk] = *(const short8v*)(xb + (long)rl * DD + kk * 32 + kg * 8);
    f32x4 acc[8];
#pragma unroll
    for (int n = 0; n < 8; ++n) acc[n] = (f32x4){0.f, 0.f, 0.f, 0.f};
#pragma unroll
    for (int n = 0; n < 8; ++n) {
#pragma unroll
        for (int kk = 0; kk < 4; ++kk) {
            short8v b = *(const short8v*)(wlds + ((n * 4 + kk) * 64 + lane) * 8);
            acc[n] = __builtin_amdgcn_mfma_f32_16x16x32_bf16(a[kk], b, acc[n], 0, 0, 0);
        }
    }
    int c0 = lane & 15;
#pragma unroll
    for (int reg = 0; reg < 4; ++reg) {
        int row = rowbase + kg * 4 + reg;
        if (row < NN) {
            float dv = dinv[row];
            unsigned short* op = outb + (long)row * DD + c0;
#pragma unroll
            for (int n = 0; n < 8; ++n) op[n * 16] = f2bf(dv * acc[n][reg]);
        }
    }
}

// ---------------- agg edge-sum body: 16/8/4/1 unroll ladder ----------------
__device__ __forceinline__ void agg_node(const unsigned int* __restrict__ hpb,
                                         const unsigned int* __restrict__ csr,
                                         int s, int e_end, unsigned int lane,
                                         float& accx, float& accy) {
    int e = s;
    for (; e + 16 <= e_end; e += 16) {
        unsigned int p0 = hpb[csr[e] + lane];
        unsigned int p1 = hpb[csr[e + 1] + lane];
        unsigned int p2 = hpb[csr[e + 2] + lane];
        unsigned int p3 = hpb[csr[e + 3] + lane];
        unsigned int p4 = hpb[csr[e + 4] + lane];
        unsigned int p5 = hpb[csr[e + 5] + lane];
        unsigned int p6 = hpb[csr[e + 6] + lane];
        unsigned int p7 = hpb[csr[e + 7] + lane];
        unsigned int q0 = hpb[csr[e + 8] + lane];
        unsigned int q1 = hpb[csr[e + 9] + lane];
        unsigned int q2 = hpb[csr[e + 10] + lane];
        unsigned int q3 = hpb[csr[e + 11] + lane];
        unsigned int q4 = hpb[csr[e + 12] + lane];
        unsigned int q5 = hpb[csr[e + 13] + lane];
        unsigned int q6 = hpb[csr[e + 14] + lane];
        unsigned int q7 = hpb[csr[e + 15] + lane];
        accx += ((bflo(p0) + bflo(p1)) + (bflo(p2) + bflo(p3))) +
                ((bflo(p4) + bflo(p5)) + (bflo(p6) + bflo(p7))) +
                ((bflo(q0) + bflo(q1)) + (bflo(q2) + bflo(q3))) +
                ((bflo(q4) + bflo(q5)) + (bflo(q6) + bflo(q7)));
        accy += ((bfhi(p0) + bfhi(p1)) + (bfhi(p2) + bfhi(p3))) +
                ((bfhi(p4) + bfhi(p5)) + (bfhi(p6) + bfhi(p7))) +
                ((bfhi(q0) + bfhi(q1)) + (bfhi(q2) + bfhi(q3))) +
                ((bfhi(q4) + bfhi(q5)) + (bfhi(q6) + bfhi(q7)));
    }
    if (e + 8 <= e_end) {
        unsigned int p0 = hpb[csr[e] + lane];
        unsigned int p1 = hpb[csr[e + 1] + lane];
        unsigned int p2 = hpb[csr[e + 2] + lane];
        unsigned int p3 = hpb[csr[e + 3] + lane];
        unsigned int p4 = hpb[csr[e + 4] + lane];
        unsigned int p5 = hpb[csr[e + 5] + lane];
        unsigned int p6 = hpb[csr[e + 6] + lane];
        unsigned int p7 = hpb[csr[e + 7] + lane];
        accx += (bflo(p0) + bflo(p1)) + (bflo(p2) + bflo(p3)) +
                (bflo(p4) + bflo(p5)) + (bflo(p6) + bflo(p7));
        accy += (bfhi(p0) + bfhi(p1)) + (bfhi(p2) + bfhi(p3)) +
                (bfhi(p4) + bfhi(p5)) + (bfhi(p6) + bfhi(p7));
        e += 8;
    }
    if (e + 4 <= e_end) {
        unsigned int p0 = hpb[csr[e] + lane];
        unsigned int p1 = hpb[csr[e + 1] + lane];
        unsigned int p2 = hpb[csr[e + 2] + lane];
        unsigned int p3 = hpb[csr[e + 3] + lane];
        accx += (bflo(p0) + bflo(p1)) + (bflo(p2) + bflo(p3));
        accy += (bfhi(p0) + bfhi(p1)) + (bfhi(p2) + bfhi(p3));
        e += 4;
    }
    for (; e < e_end; ++e) {
        unsigned int p0 = hpb[csr[e] + lane];
        accx += bflo(p0);
        accy += bfhi(p0);
    }
}

// ---------------- agg1: grid-strided wave per node -> bf16 habuf ----------------
__global__ __launch_bounds__(256) void agg_k(const unsigned int* __restrict__ hpb,
                                             const float* __restrict__ dinv,
                                             const int* __restrict__ offs,
                                             const unsigned int* __restrict__ csr,
                                             const float* __restrict__ bias,
                                             unsigned short* __restrict__ outb) {
    int wv = (blockIdx.x << 2) + (threadIdx.x >> 6);
    unsigned int lane = threadIdx.x & 63;
    float2 bb = ((const float2*)bias)[lane];
    for (int node = wv; node < NN; node += AGG_WAVES) {
        unsigned int ps = hpb[(unsigned int)node * 64u + lane];
        float accx = bflo(ps), accy = bfhi(ps);
        agg_node(hpb, csr, offs[node], offs[node + 1], lane, accx, accy);
        float dv = dinv[node];
        float ox = fmaxf(fmaf(dv, accx, bb.x), 0.0f);
        float oy = fmaxf(fmaf(dv, accy, bb.y), 0.0f);
        ((ushort2*)outb)[(unsigned int)node * 64u + lane] = make_ushort2(f2bf(ox), f2bf(oy));
    }
}

// ---------------- agg2+pool: contiguous node range per wave, boundary-flush into gsum ----------
__global__ __launch_bounds__(256) void agg2pool_k(const unsigned int* __restrict__ hpb,
                                                  const float* __restrict__ dinv,
                                                  const int* __restrict__ offs,
                                                  const unsigned int* __restrict__ csr,
                                                  const float* __restrict__ bias,
                                                  const int* __restrict__ batch,
                                                  float* __restrict__ gsum) {
    int wave = (blockIdx.x << 2) + (threadIdx.x >> 6);
    unsigned int lane = threadIdx.x & 63;
    const int per = (NN + AGG_WAVES - 1) / AGG_WAVES;  // 13
    int s = wave * per;
    int e = min(s + per, NN);
    if (s >= e) return;
    float2 bb = ((const float2*)bias)[lane];
    float2 acc = {0.0f, 0.0f};
    int cur = batch[s];
    for (int node = s; node < e; ++node) {
        int bg = batch[node];
        if (bg != cur) {
            atomicAdd(&gsum[cur * DD + 2 * lane], acc.x);
            atomicAdd(&gsum[cur * DD + 2 * lane + 1], acc.y);
            acc.x = 0.0f; acc.y = 0.0f;
            cur = bg;
        }
        unsigned int ps = hpb[(unsigned int)node * 64u + lane];
        float accx = bflo(ps), accy = bfhi(ps);
        agg_node(hpb, csr, offs[node], offs[node + 1], lane, accx, accy);
        float dv = dinv[node];
        acc.x += fmaxf(fmaf(dv, accx, bb.x), 0.0f);
        acc.y += fmaxf(fmaf(dv, accy, bb.y), 0.0f);
    }
    atomicAdd(&gsum[cur * DD + 2 * lane], acc.x);
    atomicAdd(&gsum[cur * DD + 2 * lane + 1], acc.y);
}

// ---------------- final head: inline graph-boundary binary search ----------------
__global__ __launch_bounds__(256) void final_k(const float* __restrict__ gsum, const int* __restrict__ batch,
                                               const float* __restrict__ Wlin, const float* __restrict__ blin,
                                               float* __restrict__ out) {
    int idx = blockIdx.x * 256 + threadIdx.x;
    if (idx >= NG * NC) return;
    int g = idx / NC, c = idx % NC;
    int s0, s1;
    {
        int lo = 0, hi = NN;
        while (lo < hi) { int m = (lo + hi) >> 1; if (batch[m] < g) lo = m + 1; else hi = m; }
        s0 = lo;
        lo = s0; hi = NN;
        while (lo < hi) { int m = (lo + hi) >> 1; if (batch[m] < g + 1) lo = m + 1; else hi = m; }
        s1 = lo;
    }
    int cnt = s1 - s0;
    float inv = 1.0f / fmaxf((float)cnt, 1.0f);
    float acc = blin[c];
    for (int k = 0; k < DD; ++k) acc = fmaf(gsum[g * DD + k] * inv, Wlin[k * NC + c], acc);
    out[idx] = acc;
}

extern "C" void kernel_launch(void* const* d_in, const int* in_sizes, int n_in,
                              void* d_out, int out_size, void* d_ws, size_t ws_size,
                              hipStream_t stream) {
    const float* x     = (const float*)d_in[0];
    const int*   ei    = (const int*)d_in[1];   // [2][NE]: row=src, col=dst
    const int*   batch = (const int*)d_in[2];
    const float* W1    = (const float*)d_in[3];
    const float* b1    = (const float*)d_in[4];
    const float* W2    = (const float*)d_in[5];
    const float* b2    = (const float*)d_in[6];
    const float* Wlin  = (const float*)d_in[7];
    const float* blin  = (const float*)d_in[8];
    float* out = (float*)d_out;

    const int* erow = ei;
    const int* ecol = ei + NE;

    char* ws = (char*)d_ws;
    size_t off = 0;
    auto alloc = [&](size_t bytes) {
        void* p = ws + off;
        off = (off + bytes + 255) & ~(size_t)255;
        return p;
    };
    unsigned short* hbuf  = (unsigned short*)alloc((size_t)NN * DD * 2);  // h / h' (bf16)
    unsigned short* habuf = (unsigned short*)alloc((size_t)NN * DD * 2);  // agg1 out (bf16)
    unsigned short* Wpk1  = (unsigned short*)alloc(16384 * 2);
    unsigned short* Wpk2  = (unsigned short*)alloc(16384 * 2);
    float* dinv     = (float*)alloc(NN * 4);
    int*   offs     = (int*)alloc((NN + 1) * 4);
    int*   bbase    = (int*)alloc((NB1 + 1) * 4);
    int*   hist     = (int*)alloc((size_t)NB1 * NWG1 * 4);
    int*   tmpe     = (int*)alloc((size_t)NE * 4);
    unsigned int* csrsrc = (unsigned int*)alloc((size_t)NE * 4);
    float* gsum     = (float*)alloc(NG * DD * 4);
    (void)ws_size; (void)in_sizes; (void)n_in; (void)out_size;

    // K0: hist | pack W1 | pack W2 | gsum zero
    k0_fused<<<NWG1 + 3, 256, 0, stream>>>(ecol, hist, W1, W2, Wpk1, Wpk2, gsum);
    btot_k<<<1, 512, 0, stream>>>(hist, bbase);
    histscan_k<<<NB1, 256, 0, stream>>>(bbase, hist);
    // K3: part1 | gemm1 (independent once histscan done; gemm1 needs only x + Wpk1)
    k3_fused<<<NWG1 + GEMM_BLOCKS, 256, 0, stream>>>(erow, ecol, hist, tmpe, x, Wpk1, hbuf);
    // part2b: offs/dinv/csr build AND dinv-scale of its own hbuf rows
    part2b_k<<<NB1, 512, 0, stream>>>(bbase, tmpe, csrsrc, offs, dinv, (unsigned int*)hbuf);

    // layer 1 aggregate: hbuf -> habuf
    agg_k<<<AGG_WAVES / 4, 256, 0, stream>>>((const unsigned int*)hbuf, dinv, offs, csrsrc, b1, habuf);
    // layer 2: habuf -> hbuf (gemm, dinv-scaled) -> gsum (agg+relu+pool fused)
    gemm2_k<<<GEMM_BLOCKS, 256, 0, stream>>>(habuf, Wpk2, dinv, hbuf);
    agg2pool_k<<<AGG_WAVES / 4, 256, 0, stream>>>((const unsigned int*)hbuf, dinv, offs, csrsrc, b2,
                                                  batch, gsum);
    final_k<<<(NG * NC + 255) / 256, 256, 0, stream>>>(gsum, batch, Wlin, blin, out);
}